// Round 22
// baseline (39528.357 us; speedup 1.0000x reference)
//
#include <hip/hip_runtime.h>
#include <math.h>

#define B_ 32
#define N_ 512
#define D_ 768
#define H_ 1024
#define NB 8             // batches per group
#define M8 (NB*N_)       // 4096 staging rows per group
#define J_SS 16          // smoothstep iterations (transition +-1.0%)
#define J_NEWT 15        // scaled-Newton iterations (residual ~1e-7)
#define POW_ITERS 60
// (jax f32 pinv rtol)^2 = (10 * 512 * 2^-23)^2
#define RTOL2 3.725290298461914e-7

typedef double dx4 __attribute__((ext_vector_type(4)));

// ---------------------------------------------------------------------------
#if __has_builtin(__builtin_amdgcn_mfma_f64_16x16x4f64)
__device__ __forceinline__ dx4 mfma64(double a, double b, dx4 c) {
  return __builtin_amdgcn_mfma_f64_16x16x4f64(a, b, c, 0, 0, 0);
}
#else
// No builtin: probe sees zeros -> flag=4 -> VALU path used everywhere.
__device__ __forceinline__ dx4 mfma64(double a, double b, dx4 c) { return c; }
#endif

// ---------------------------------------------------------------------------
// On-device MFMA D-layout probe (flag=4 -> VALU fallback).
// ---------------------------------------------------------------------------
__global__ __launch_bounds__(64) void mfma_probe(int* __restrict__ flag)
{
  const int l = threadIdx.x;
  const int lk = l >> 4;
  dx4 d1 = {}; d1 = mfma64((double)(l & 15), 1.0, d1);
  dx4 d2 = {}; d2 = mfma64(1.0, (double)(l & 15), d2);
  dx4 d3 = {}; d3 = mfma64((lk == 0) ? 1.0 : 0.0, (double)(lk + 1), d3);
  __shared__ double s1[256];
  __shared__ double s2[256];
  __shared__ double s3[256];
  #pragma unroll
  for (int e = 0; e < 4; ++e) { s1[l*4+e] = d1[e]; s2[l*4+e] = d2[e]; s3[l*4+e] = d3[e]; }
  __syncthreads();
  if (l == 0) {
    int f = 4;
    for (int c = 0; c < 4 && f == 4; ++c) {
      bool ok = true;
      for (int q = 0; q < 64 && ok; ++q) {
        for (int r = 0; r < 4 && ok; ++r) {
          int mi, ni;
          if (c == 0)      { mi = 4*(q>>4)+r; ni = q & 15; }
          else if (c == 1) { mi = (q>>4)+4*r; ni = q & 15; }
          else if (c == 2) { mi = q & 15; ni = 4*(q>>4)+r; }
          else             { mi = q & 15; ni = (q>>4)+4*r; }
          if (s1[q*4+r] != (double)(4*mi)) ok = false;
          if (s2[q*4+r] != (double)(4*ni)) ok = false;
          if (s3[q*4+r] != 1.0) ok = false;
        }
      }
      if (ok) f = c;
    }
    *flag = f;
  }
}

// ---------------------------------------------------------------------------
template<typename T>
__device__ inline void load4d(const T* __restrict__ p, double* d) {
  if constexpr (sizeof(T) == 4) {
    const float4 v = *(const float4*)p;
    d[0] = v.x; d[1] = v.y; d[2] = v.z; d[3] = v.w;
  } else {
    const double2 a = *(const double2*)p;
    const double2 b = *(const double2*)(p + 2);
    d[0] = a.x; d[1] = a.y; d[2] = b.x; d[3] = b.y;
  }
}

// ---------------------------------------------------------------------------
// LDS ping-pong GEMM driver, BK=16, ONE barrier per chunk.
// ld(k0, r): global -> regs.  st(k0, r, A, B): regs -> given LDS buffer.
// epi(mi, ni, v): consume result.  flagv 0..3 MFMA D-conv, 4 VALU.
// Invariant at top of iter k: buf[cur] holds chunk k, all waves past B(k-1).
// ---------------------------------------------------------------------------
template<int NR, typename FLD, typename FST, typename FE>
__device__ __forceinline__ void run_gemm_pp(int K, int flagv, int t,
    double (*As)[16][66], double (*Bs)[16][66], FLD ld, FST st, FE epi)
{
  const int lane = t & 63; const int wid = t >> 6;
  const int wr = (wid >> 1) << 5; const int wc = (wid & 1) << 5;
  const int lr = lane & 15; const int lk = lane >> 4;
  double r[NR];
  ld(0, r);
  st(0, r, As[0], Bs[0]);
  __syncthreads();
  int cur = 0;
  if (flagv < 4) {
    dx4 acc[2][2] = {};
    for (int k0 = 0; k0 < K; k0 += 16) {
      const bool more = (k0 + 16 < K);
      if (more) ld(k0 + 16, r);
      #pragma unroll
      for (int kq = 0; kq < 4; ++kq) {
        const int kr = (kq << 2) + lk;
        const double a0 = As[cur][kr][wr + lr];
        const double a1 = As[cur][kr][wr + 16 + lr];
        const double b0 = Bs[cur][kr][wc + lr];
        const double b1 = Bs[cur][kr][wc + 16 + lr];
        acc[0][0] = mfma64(a0, b0, acc[0][0]);
        acc[0][1] = mfma64(a0, b1, acc[0][1]);
        acc[1][0] = mfma64(a1, b0, acc[1][0]);
        acc[1][1] = mfma64(a1, b1, acc[1][1]);
      }
      if (more) {
        st(k0 + 16, r, As[cur ^ 1], Bs[cur ^ 1]);
        __syncthreads();
        cur ^= 1;
      }
    }
    #pragma unroll
    for (int tm = 0; tm < 2; ++tm)
    #pragma unroll
    for (int tn = 0; tn < 2; ++tn)
    #pragma unroll
    for (int i = 0; i < 4; ++i) {
      int mo, no;
      if (flagv == 0)      { mo = (lk << 2) + i; no = lr; }
      else if (flagv == 1) { mo = lk + (i << 2); no = lr; }
      else if (flagv == 2) { mo = lr; no = (lk << 2) + i; }
      else                 { mo = lr; no = lk + (i << 2); }
      epi(wr + tm*16 + mo, wc + tn*16 + no, acc[tm][tn][i]);
    }
  } else {
    const int tx = t & 15, ty = t >> 4;
    double acc[4][4] = {};
    for (int k0 = 0; k0 < K; k0 += 16) {
      const bool more = (k0 + 16 < K);
      if (more) ld(k0 + 16, r);
      #pragma unroll
      for (int kk = 0; kk < 16; ++kk) {
        double av[4], bv[4];
        #pragma unroll
        for (int q = 0; q < 4; ++q) { av[q] = As[cur][kk][(ty<<2)+q]; bv[q] = Bs[cur][kk][(tx<<2)+q]; }
        #pragma unroll
        for (int ii = 0; ii < 4; ++ii)
          #pragma unroll
          for (int jj = 0; jj < 4; ++jj)
            acc[ii][jj] = fma(av[ii], bv[jj], acc[ii][jj]);
      }
      if (more) {
        st(k0 + 16, r, As[cur ^ 1], Bs[cur ^ 1]);
        __syncthreads();
        cur ^= 1;
      }
    }
    #pragma unroll
    for (int ii = 0; ii < 4; ++ii)
      #pragma unroll
      for (int jj = 0; jj < 4; ++jj)
        epi((ty << 2) + ii, (tx << 2) + jj, acc[ii][jj]);
  }
}

// Dual-accumulator ping-pong variant (final64): epi(mi, ni, vy, vz).
template<int NR, typename FLD, typename FST, typename FE>
__device__ __forceinline__ void run_gemm2_pp(int K, int flagv, int t,
    double (*Ps)[16][66], double (*W1)[16][66], double (*W2)[16][66],
    FLD ld, FST st, FE epi)
{
  const int lane = t & 63; const int wid = t >> 6;
  const int wr = (wid >> 1) << 5; const int wc = (wid & 1) << 5;
  const int lr = lane & 15; const int lk = lane >> 4;
  double r[NR];
  ld(0, r);
  st(0, r, Ps[0], W1[0], W2[0]);
  __syncthreads();
  int cur = 0;
  if (flagv < 4) {
    dx4 accY[2][2] = {};
    dx4 accZ[2][2] = {};
    for (int k0 = 0; k0 < K; k0 += 16) {
      const bool more = (k0 + 16 < K);
      if (more) ld(k0 + 16, r);
      #pragma unroll
      for (int kq = 0; kq < 4; ++kq) {
        const int kr = (kq << 2) + lk;
        const double a0 = Ps[cur][kr][wr + lr];
        const double a1 = Ps[cur][kr][wr + 16 + lr];
        const double y0 = W1[cur][kr][wc + lr];
        const double y1 = W1[cur][kr][wc + 16 + lr];
        const double z0 = W2[cur][kr][wc + lr];
        const double z1 = W2[cur][kr][wc + 16 + lr];
        accY[0][0] = mfma64(a0, y0, accY[0][0]);
        accY[0][1] = mfma64(a0, y1, accY[0][1]);
        accY[1][0] = mfma64(a1, y0, accY[1][0]);
        accY[1][1] = mfma64(a1, y1, accY[1][1]);
        accZ[0][0] = mfma64(a0, z0, accZ[0][0]);
        accZ[0][1] = mfma64(a0, z1, accZ[0][1]);
        accZ[1][0] = mfma64(a1, z0, accZ[1][0]);
        accZ[1][1] = mfma64(a1, z1, accZ[1][1]);
      }
      if (more) {
        st(k0 + 16, r, Ps[cur ^ 1], W1[cur ^ 1], W2[cur ^ 1]);
        __syncthreads();
        cur ^= 1;
      }
    }
    #pragma unroll
    for (int tm = 0; tm < 2; ++tm)
    #pragma unroll
    for (int tn = 0; tn < 2; ++tn)
    #pragma unroll
    for (int i = 0; i < 4; ++i) {
      int mo, no;
      if (flagv == 0)      { mo = (lk << 2) + i; no = lr; }
      else if (flagv == 1) { mo = lk + (i << 2); no = lr; }
      else if (flagv == 2) { mo = lr; no = (lk << 2) + i; }
      else                 { mo = lr; no = lk + (i << 2); }
      epi(wr + tm*16 + mo, wc + tn*16 + no, accY[tm][tn][i], accZ[tm][tn][i]);
    }
  } else {
    const int tx = t & 15, ty = t >> 4;
    double aY[4][4] = {};
    double aZ[4][4] = {};
    for (int k0 = 0; k0 < K; k0 += 16) {
      const bool more = (k0 + 16 < K);
      if (more) ld(k0 + 16, r);
      #pragma unroll
      for (int kk = 0; kk < 16; ++kk) {
        double av[4], y[4], z[4];
        #pragma unroll
        for (int q = 0; q < 4; ++q) {
          av[q] = Ps[cur][kk][(ty<<2)+q]; y[q] = W1[cur][kk][(tx<<2)+q]; z[q] = W2[cur][kk][(tx<<2)+q];
        }
        #pragma unroll
        for (int ii = 0; ii < 4; ++ii)
          #pragma unroll
          for (int jj = 0; jj < 4; ++jj) {
            aY[ii][jj] = fma(av[ii], y[jj], aY[ii][jj]);
            aZ[ii][jj] = fma(av[ii], z[jj], aZ[ii][jj]);
          }
      }
      if (more) {
        st(k0 + 16, r, Ps[cur ^ 1], W1[cur ^ 1], W2[cur ^ 1]);
        __syncthreads();
        cur ^= 1;
      }
    }
    #pragma unroll
    for (int ii = 0; ii < 4; ++ii)
      #pragma unroll
      for (int jj = 0; jj < 4; ++jj)
        epi((ty << 2) + ii, (tx << 2) + jj, aY[ii][jj], aZ[ii][jj]);
  }
}

// ---------------------------------------------------------------------------
// f64 tiled GEMM, mixed input types, f64 output.
// EPI: 0 none; 1 tanh(v + bias[n]); 2 (m==n ? 0 : exp(v))
// ---------------------------------------------------------------------------
template<typename TA, typename TB, int TRANSB, int EPI>
__global__ __launch_bounds__(256) void gemm64(
    const TA* __restrict__ A, const TB* __restrict__ Bm,
    const float* __restrict__ bias, double* __restrict__ C,
    int M, int Nn, int K, size_t sA, size_t sB, size_t sC,
    const int* __restrict__ flagp)
{
  A  += (size_t)blockIdx.z * sA;
  Bm += (size_t)blockIdx.z * sB;
  C  += (size_t)blockIdx.z * sC;
  __shared__ double As[2][16][66];
  __shared__ double Bs[2][16][66];
  const int t  = threadIdx.x;
  const int m0 = blockIdx.y * 64, n0 = blockIdx.x * 64;
  const int flagv = *flagp;
  auto ld = [&](int k0, double* r) {
    const int ml = t >> 2; const int kc = (t & 3) << 2;
    load4d(A + (size_t)(m0 + ml) * K + k0 + kc, r);
    if (TRANSB) {
      const int nl = t >> 2;
      load4d(Bm + (size_t)(n0 + nl) * K + k0 + kc, r + 4);
    } else {
      const int kl = t >> 4; const int nc = (t & 15) << 2;
      load4d(Bm + (size_t)(k0 + kl) * Nn + n0 + nc, r + 4);
    }
  };
  auto st = [&](int k0, double* r, double (*Ad)[66], double (*Bd)[66]) {
    const int ml = t >> 2; const int kc = (t & 3) << 2;
    #pragma unroll
    for (int q = 0; q < 4; ++q) Ad[kc+q][ml] = r[q];
    if (TRANSB) {
      const int nl = t >> 2;
      #pragma unroll
      for (int q = 0; q < 4; ++q) Bd[kc+q][nl] = r[4+q];
    } else {
      const int kl = t >> 4; const int nc = (t & 15) << 2;
      #pragma unroll
      for (int q = 0; q < 4; ++q) Bd[kl][nc+q] = r[4+q];
    }
  };
  auto epi = [&](int mi, int ni, double v) {
    const int m = m0 + mi; const int n = n0 + ni;
    if constexpr (EPI == 1) v = tanh(v + (double)bias[n]);
    if constexpr (EPI == 2) v = (m == n) ? 0.0 : exp(v);
    C[(size_t)m * Nn + n] = v;
  };
  run_gemm_pp<8>(K, flagv, t, As, Bs, ld, st, epi);
}

// ---------------------------------------------------------------------------
__global__ __launch_bounds__(256) void rexp_kernel(
    const float* __restrict__ x, const float* __restrict__ WR,
    const float* __restrict__ bR, double* __restrict__ rex)
{
  const int b = blockIdx.x, t = threadIdx.x;
  const float* xb = x + (size_t)b * N_ * D_;
  double s = 0.0;
  for (int d = t; d < D_; d += 256) s += (double)xb[d] * (double)WR[d];
  __shared__ double sm[256];
  sm[t] = s; __syncthreads();
  for (int o = 128; o > 0; o >>= 1) { if (t < o) sm[t] += sm[t + o]; __syncthreads(); }
  if (t == 0) rex[b] = exp(sm[0] + (double)bR[0]);
}

// ---------------------------------------------------------------------------
__global__ __launch_bounds__(256) void colsum64(
    const double* __restrict__ P, double* __restrict__ cs)
{
  const int bl = blockIdx.y;
  const int j = blockIdx.x * 256 + threadIdx.x;
  const double* Pb = P + (size_t)bl * N_ * N_;
  double s0 = 0.0, s1 = 0.0, s2 = 0.0, s3 = 0.0;
  for (int i = 0; i < N_; i += 4) {
    s0 += Pb[(size_t)(i+0) * N_ + j];
    s1 += Pb[(size_t)(i+1) * N_ + j];
    s2 += Pb[(size_t)(i+2) * N_ + j];
    s3 += Pb[(size_t)(i+3) * N_ + j];
  }
  cs[bl * N_ + j] = (s0 + s1) + (s2 + s3);
}

// ---------------------------------------------------------------------------
// PT = P^T (per batch), 32x32 LDS tiles. PT[k][i] = P[i][k].
// ---------------------------------------------------------------------------
__global__ __launch_bounds__(256) void transpose64(
    const double* __restrict__ P, double* __restrict__ PT)
{
  __shared__ double tile[32][33];
  const int bl = blockIdx.z;
  const double* Pb = P + (size_t)bl * N_ * N_;
  double* Tb = PT + (size_t)bl * N_ * N_;
  const int x0 = blockIdx.x * 32, y0 = blockIdx.y * 32;
  const int tx = threadIdx.x & 31, ty = threadIdx.x >> 5;   // 32 x 8
  #pragma unroll
  for (int r = 0; r < 32; r += 8)
    tile[ty + r][tx] = Pb[(size_t)(y0 + ty + r) * N_ + x0 + tx];
  __syncthreads();
  #pragma unroll
  for (int r = 0; r < 32; r += 8)
    Tb[(size_t)(x0 + ty + r) * N_ + y0 + tx] = tile[tx][ty + r];
}

// ---------------------------------------------------------------------------
// Power iteration on L^T L (virtual L) -> theta2[bl] = RTOL2 * sigma_max^2
// ---------------------------------------------------------------------------
__global__ __launch_bounds__(512) void powiter(
    const double* __restrict__ P, const double* __restrict__ PT,
    const double* __restrict__ cs, const double* __restrict__ rex,
    double* __restrict__ theta2, int b0)
{
  const int bl = blockIdx.x, t = threadIdx.x;
  const double* Pb  = P  + (size_t)bl * N_ * N_;
  const double* PTb = PT + (size_t)bl * N_ * N_;
  const double* csb = cs + (size_t)bl * N_;
  const double rx = rex[b0 + bl];
  __shared__ double v[N_], y[N_], red[512];
  v[t] = 1.0; __syncthreads();
  double sig2 = 0.0;
  for (int it = 0; it < POW_ITERS; ++it) {
    red[t] = v[t]; __syncthreads();
    for (int o = 256; o > 0; o >>= 1) { if (t < o) red[t] += red[t+o]; __syncthreads(); }
    const double sumv = red[0];
    double s;
    if (t == 0) s = rx * sumv;
    else {
      s = csb[t] * v[t];
      double d0 = 0.0, d1 = 0.0, d2 = 0.0, d3 = 0.0;
      for (int k = 0; k < N_; k += 4) {
        d0 += PTb[(size_t)(k+0) * N_ + t] * v[k+0];
        d1 += PTb[(size_t)(k+1) * N_ + t] * v[k+1];
        d2 += PTb[(size_t)(k+2) * N_ + t] * v[k+2];
        d3 += PTb[(size_t)(k+3) * N_ + t] * v[k+3];
      }
      s -= (d0 + d1) + (d2 + d3);
    }
    __syncthreads();
    y[t] = s; __syncthreads();
    const double y0 = y[0];
    double z = rx * y0 + ((t > 0) ? csb[t] * y[t] : 0.0) + Pb[t] * y0;
    {
      double d0 = 0.0, d1 = 0.0, d2 = 0.0, d3 = 0.0;
      for (int i = 0; i < N_; i += 4) {
        d0 += Pb[(size_t)(i+0) * N_ + t] * y[i+0];
        d1 += Pb[(size_t)(i+1) * N_ + t] * y[i+1];
        d2 += Pb[(size_t)(i+2) * N_ + t] * y[i+2];
        d3 += Pb[(size_t)(i+3) * N_ + t] * y[i+3];
      }
      z -= (d0 + d1) + (d2 + d3);
    }
    red[t] = z * z; __syncthreads();
    for (int o = 256; o > 0; o >>= 1) { if (t < o) red[t] += red[t+o]; __syncthreads(); }
    const double nz = sqrt(red[0]);
    sig2 = nz;
    v[t] = z / nz; __syncthreads();
  }
  if (t == 0) theta2[bl] = RTOL2 * sig2;
}

// ---------------------------------------------------------------------------
// S = L L^T + theta2 * I   (virtual L)
// ---------------------------------------------------------------------------
__global__ __launch_bounds__(256) void syrk64(
    const double* __restrict__ P, const double* __restrict__ cs,
    const double* __restrict__ rex, const double* __restrict__ th2,
    double* __restrict__ S, int b0, const int* __restrict__ flagp)
{
  const int bl = blockIdx.z;
  const double* Pb  = P + (size_t)bl * N_ * N_;
  const double* csb = cs + (size_t)bl * N_;
  const double rx = rex[b0 + bl];
  double* Sb = S + (size_t)bl * N_ * N_;
  __shared__ double As[2][16][66];
  __shared__ double Bs[2][16][66];
  const int t  = threadIdx.x;
  const int i0 = blockIdx.y * 64, j0 = blockIdx.x * 64;
  const int flagv = *flagp;
  const double l2 = th2[bl];
  auto ld = [&](int k0, double* r) {
    const int ml = t >> 2; const int kc = (t & 3) << 2;
    load4d(Pb + (size_t)(i0 + ml) * N_ + k0 + kc, r);
    load4d(Pb + (size_t)(j0 + ml) * N_ + k0 + kc, r + 4);
  };
  auto st = [&](int k0, double* r, double (*Ad)[66], double (*Bd)[66]) {
    const int ml = t >> 2; const int kc = (t & 3) << 2;
    const int i = i0 + ml;
    #pragma unroll
    for (int q = 0; q < 4; ++q) {
      const int k = k0 + kc + q;
      Ad[kc+q][ml] = (i == 0) ? rx : ((i == k) ? csb[k] : -r[q]);
    }
    const int j = j0 + ml;
    #pragma unroll
    for (int q = 0; q < 4; ++q) {
      const int k = k0 + kc + q;
      Bd[kc+q][ml] = (j == 0) ? rx : ((j == k) ? csb[k] : -r[4+q]);
    }
  };
  auto epi = [&](int mi, int ni, double v) {
    const int ig = i0 + mi; const int jg = j0 + ni;
    if (ig == jg) v += l2;
    Sb[(size_t)ig * N_ + jg] = v;
  };
  run_gemm_pp<8>(N_, flagv, t, As, Bs, ld, st, epi);
}

// ---------------------------------------------------------------------------
// Newton init: X0 = I / (1.1 * lambda_max),  lambda_max = th2*(1+RTOL2)/RTOL2.
// ---------------------------------------------------------------------------
__global__ __launch_bounds__(256) void newton_init(
    const double* __restrict__ th2, double* __restrict__ X)
{
  const size_t idx = (size_t)blockIdx.x * 256 + threadIdx.x;
  const int bl  = (int)(idx >> 18);
  const int rem = (int)(idx & ((size_t)N_ * N_ - 1));
  const double c = RTOL2 / (1.1 * th2[bl] * (1.0 + RTOL2));
  X[idx] = ((rem >> 9) == (rem & (N_ - 1))) ? c : 0.0;
}

// ---------------------------------------------------------------------------
// Ctik[i,j] = sum_k L[k,i] * Sinv[k,j]   (Ctik = L^T Sinv, virtual L)
// ---------------------------------------------------------------------------
__global__ __launch_bounds__(256) void linv64(
    const double* __restrict__ P, const double* __restrict__ cs,
    const double* __restrict__ rex, const double* __restrict__ Sinv,
    double* __restrict__ Out, int b0, const int* __restrict__ flagp)
{
  const int bl = blockIdx.z;
  const double* Pb  = P + (size_t)bl * N_ * N_;
  const double* csb = cs + (size_t)bl * N_;
  const double rx = rex[b0 + bl];
  const double* Sb = Sinv + (size_t)bl * N_ * N_;
  double* Ob = Out + (size_t)bl * N_ * N_;
  __shared__ double As[2][16][66];   // [k][i] = L[k0+k][i0+i]
  __shared__ double Bs[2][16][66];   // [k][j] = Sinv[k0+k][j0+j]
  const int t  = threadIdx.x;
  const int i0 = blockIdx.y * 64, j0 = blockIdx.x * 64;
  const int flagv = *flagp;
  auto ld = [&](int k0, double* r) {
    const int kl = t >> 4; const int c4 = (t & 15) << 2;
    const int k = k0 + kl;
    load4d(Pb + (size_t)k * N_ + i0 + c4, r);
    load4d(Sb + (size_t)k * N_ + j0 + c4, r + 4);
  };
  auto st = [&](int k0, double* r, double (*Ad)[66], double (*Bd)[66]) {
    const int kl = t >> 4; const int c4 = (t & 15) << 2;
    const int k = k0 + kl;
    #pragma unroll
    for (int q = 0; q < 4; ++q) {
      const int i = i0 + c4 + q;
      Ad[kl][c4+q] = (k == 0) ? rx : ((k == i) ? csb[k] : -r[q]);
    }
    #pragma unroll
    for (int q = 0; q < 4; ++q) Bd[kl][c4+q] = r[4+q];
  };
  auto epi = [&](int mi, int ni, double v) {
    Ob[(size_t)(i0 + mi) * N_ + j0 + ni] = v;
  };
  run_gemm_pp<8>(N_, flagv, t, As, Bs, ld, st, epi);
}

// ---------------------------------------------------------------------------
// Ghat = A * L_virtual.  Fused epilogue also emits D = I - G and R0 = 2I - G.
// ---------------------------------------------------------------------------
__global__ __launch_bounds__(256) void ghat64(
    const double* __restrict__ A, const double* __restrict__ P,
    const double* __restrict__ cs, const double* __restrict__ rex,
    double* __restrict__ OutG, double* __restrict__ OutD,
    double* __restrict__ OutR, int b0, const int* __restrict__ flagp)
{
  const int bl = blockIdx.z;
  const double* Ab  = A + (size_t)bl * N_ * N_;
  const double* Pb  = P + (size_t)bl * N_ * N_;
  const double* csb = cs + (size_t)bl * N_;
  const double rx = rex[b0 + bl];
  double* Gb = OutG + (size_t)bl * N_ * N_;
  double* Db = OutD + (size_t)bl * N_ * N_;
  double* Rb = OutR + (size_t)bl * N_ * N_;
  __shared__ double As[2][16][66];
  __shared__ double Bs[2][16][66];
  const int t  = threadIdx.x;
  const int m0 = blockIdx.y * 64, n0 = blockIdx.x * 64;
  const int flagv = *flagp;
  auto ld = [&](int k0, double* r) {
    const int ml = t >> 2; const int kc = (t & 3) << 2;
    load4d(Ab + (size_t)(m0 + ml) * N_ + k0 + kc, r);
    const int kl = t >> 4; const int nc = (t & 15) << 2;
    load4d(Pb + (size_t)(k0 + kl) * N_ + n0 + nc, r + 4);
  };
  auto st = [&](int k0, double* r, double (*Ad)[66], double (*Bd)[66]) {
    const int ml = t >> 2; const int kc = (t & 3) << 2;
    #pragma unroll
    for (int q = 0; q < 4; ++q) Ad[kc+q][ml] = r[q];
    const int kl = t >> 4; const int nc = (t & 15) << 2;
    const int k = k0 + kl;
    #pragma unroll
    for (int q = 0; q < 4; ++q) {
      const int n = n0 + nc + q;
      Bd[kl][nc+q] = (k == 0) ? rx : ((k == n) ? csb[k] : -r[4+q]);
    }
  };
  auto epi = [&](int mi, int ni, double v) {
    const int m = m0 + mi; const int n = n0 + ni;
    const double di = (m == n) ? 1.0 : 0.0;
    const size_t off = (size_t)m * N_ + n;
    Gb[off] = v;
    Db[off] = di - v;         // D = I - G
    Rb[off] = 2.0 * di - v;   // R0 = 2I - G
  };
  run_gemm_pp<8>(N_, flagv, t, As, Bs, ld, st, epi);
}

// ---------------------------------------------------------------------------
// f64 NN GEMM (batched stride N*N), full grid.
// EPI 0: C = A*B.               EPI 2: C = 3*A - 2*A*B  (smoothstep).
// EPI 4: C = 2g*A - g^2*A*B     (scaled Newton, g runtime).
// EPI 5: C = A + A*B            (Horner product accumulate).
// ---------------------------------------------------------------------------
template<int EPI>
__global__ __launch_bounds__(256) void gemm_dd(
    const double* __restrict__ A, const double* __restrict__ Bm,
    double* __restrict__ C, const int* __restrict__ flagp, double g)
{
  const size_t s = (size_t)N_ * N_;
  const double* Ab = A  + (size_t)blockIdx.z * s;
  const double* Bb = Bm + (size_t)blockIdx.z * s;
  double*       Cb = C  + (size_t)blockIdx.z * s;
  __shared__ double As[2][16][66];
  __shared__ double Bs[2][16][66];
  const int t  = threadIdx.x;
  const int m0 = blockIdx.y * 64, n0 = blockIdx.x * 64;
  const int flagv = *flagp;
  auto ld = [&](int k0, double* r) {
    const int ml = t >> 2; const int kc = (t & 3) << 2;
    load4d(Ab + (size_t)(m0 + ml) * N_ + k0 + kc, r);
    const int kl = t >> 4; const int nc = (t & 15) << 2;
    load4d(Bb + (size_t)(k0 + kl) * N_ + n0 + nc, r + 4);
  };
  auto st = [&](int k0, double* r, double (*Ad)[66], double (*Bd)[66]) {
    const int ml = t >> 2; const int kc = (t & 3) << 2;
    #pragma unroll
    for (int q = 0; q < 4; ++q) Ad[kc+q][ml] = r[q];
    const int kl = t >> 4; const int nc = (t & 15) << 2;
    #pragma unroll
    for (int q = 0; q < 4; ++q) Bd[kl][nc+q] = r[4+q];
  };
  auto epi = [&](int mi, int ni, double v) {
    const int m = m0 + mi; const int n = n0 + ni;
    if constexpr (EPI == 2) v = 3.0 * Ab[(size_t)m * N_ + n] - 2.0 * v;
    if constexpr (EPI == 4) v = 2.0 * g * Ab[(size_t)m * N_ + n] - g * g * v;
    if constexpr (EPI == 5) v = Ab[(size_t)m * N_ + n] + v;
    Cb[(size_t)m * N_ + n] = v;
  };
  run_gemm_pp<8>(N_, flagv, t, As, Bs, ld, st, epi);
}

// ---------------------------------------------------------------------------
// out[bl,i,j] = (j>0)*(P @ C)[i,j] - (i>0)*(P @ C^T)[i,j]
// ---------------------------------------------------------------------------
__global__ __launch_bounds__(256) void final64(
    const double* __restrict__ P, const double* __restrict__ X,
    float* __restrict__ Out, const int* __restrict__ flagp)
{
  const int bl = blockIdx.z;
  const double* Pb = P + (size_t)bl * N_ * N_;
  const double* Ib = X + (size_t)bl * N_ * N_;
  float*        Ob = Out + (size_t)bl * N_ * N_;
  __shared__ double Ps[2][16][66];
  __shared__ double W1[2][16][66];
  __shared__ double W2[2][16][66];
  const int t  = threadIdx.x;
  const int m0 = blockIdx.y * 64, n0 = blockIdx.x * 64;
  const int flagv = *flagp;
  auto ld = [&](int k0, double* r) {
    const int ml = t >> 2; const int kc = (t & 3) << 2;
    load4d(Pb + (size_t)(m0 + ml) * N_ + k0 + kc, r);
    load4d(Ib + (size_t)(n0 + ml) * N_ + k0 + kc, r + 4);
    const int kl = t >> 4; const int nc = (t & 15) << 2;
    load4d(Ib + (size_t)(k0 + kl) * N_ + n0 + nc, r + 8);
  };
  auto st = [&](int k0, double* r, double (*Pd)[66], double (*W1d)[66], double (*W2d)[66]) {
    const int ml = t >> 2; const int kc = (t & 3) << 2;
    #pragma unroll
    for (int q = 0; q < 4; ++q) Pd[kc+q][ml] = r[q];
    #pragma unroll
    for (int q = 0; q < 4; ++q) W2d[kc+q][ml] = r[4+q];
    const int kl = t >> 4; const int nc = (t & 15) << 2;
    #pragma unroll
    for (int q = 0; q < 4; ++q) W1d[kl][nc+q] = r[8+q];
  };
  auto epi = [&](int mi, int ni, double vy, double vz) {
    const int m = m0 + mi; const int n = n0 + ni;
    double v = 0.0;
    if (n > 0) v += vy;
    if (m > 0) v -= vz;
    Ob[(size_t)m * N_ + n] = (float)v;
  };
  run_gemm2_pp<12>(N_, flagv, t, Ps, W1, W2, ld, st, epi);
}

// ---------------------------------------------------------------------------
extern "C" void kernel_launch(void* const* d_in, const int* in_sizes, int n_in,
                              void* d_out, int out_size, void* d_ws, size_t ws_size,
                              hipStream_t stream)
{
  const float* x    = (const float*)d_in[0];
  const float* W_P  = (const float*)d_in[1];
  const float* b_P  = (const float*)d_in[2];
  const float* W_C  = (const float*)d_in[3];
  const float* b_C  = (const float*)d_in[4];
  const float* W_bl = (const float*)d_in[5];
  const float* W_R  = (const float*)d_in[6];
  const float* b_R  = (const float*)d_in[7];
  float* out = (float*)d_out;
  char*  ws8 = (char*)d_ws;

  // Workspace (bytes), peak ~144.1 MB:
  double* encS = (double*)(ws8 + 0);           // 32 MB encP/encC -> Gd, Dd
  double* Tst  = (double*)(ws8 + 33554432);    // 32 MB T8 -> PT -> Ra, Rb
  double* P8   = (double*)(ws8 + 67108864);    // 16 MB
  double* Md   = (double*)(ws8 + 83886080);    // 16 MB S (const through Newton)
  double* Vd   = (double*)(ws8 + 100663296);   // 16 MB X ping
  double* Ctik = (double*)(ws8 + 117440512);   // 16 MB T temp -> Ctik
  double* C1d  = (double*)(ws8 + 134217728);   // 16 MB X pong (ends=Sinv) -> C1
  double* csg  = (double*)(ws8 + 150994944);   // 32 KB
  double* th2  = (double*)(ws8 + 151027712);   // 64 B
  double* rex  = (double*)(ws8 + 151027776);   // 256 B
  int*    flagp= (int*)   (ws8 + 151028032);   // 4 B : MFMA layout flag
  double* Gd   = (double*)(ws8 + 0);
  double* Dd   = (double*)(ws8 + 16777216);
  double* Ra   = (double*)(ws8 + 33554432);
  double* Rb   = (double*)(ws8 + 50331648);
  double* PTd  = (double*)(ws8 + 33554432);    // PT aliases Tst/Ra (dead then)

  // Host-computed scaled-Newton gamma schedule (data-independent).
  double gam[J_NEWT];
  {
    double a = RTOL2 / (1.1 * (1.0 + RTOL2));
    double b = (1.0 / 1.1) * 1.08;
    for (int k = 0; k < J_NEWT; ++k) {
      double g = 2.0 / (a + b);
      if (g < 1.0) g = 1.0;
      gam[k] = g;
      double ga = g * a;
      a = ga * (2.0 - ga);
      if (a > 1.0) a = 1.0;
      b = 1.0;
    }
  }

  const dim3 blk(256);
  const size_t sNH = (size_t)N_ * H_;
  const size_t sNN = (size_t)N_ * N_;
  const dim3 g64(N_/64, N_/64, NB);
  const dim3 gEw((NB * N_ * N_) / 256);

  // On-device MFMA D-layout probe (4 conventions + VALU fallback).
  mfma_probe<<<dim3(1), dim3(64), 0, stream>>>(flagp);
  rexp_kernel<<<dim3(B_), blk, 0, stream>>>(x, W_R, b_R, rex);

  for (int g = 0; g < 4; ++g) {
    const int b0 = g * NB;
    const float* xg = x + (size_t)b0 * N_ * D_;
    // ---- upstream (f64) ----
    gemm64<float,float,1,1><<<dim3(H_/64, M8/64, 1), blk, 0, stream>>>(
        xg, W_P, b_P, encS, M8, H_, D_, 0, 0, 0, flagp);
    gemm64<double,float,0,0><<<dim3(H_/64, M8/64, 1), blk, 0, stream>>>(
        encS, W_bl, nullptr, Tst, M8, H_, H_, 0, 0, 0, flagp);
    gemm64<float,float,1,1><<<dim3(H_/64, M8/64, 1), blk, 0, stream>>>(
        xg, W_C, b_C, encS, M8, H_, D_, 0, 0, 0, flagp);
    gemm64<double,double,1,2><<<g64, blk, 0, stream>>>(
        Tst, encS, nullptr, P8, N_, N_, H_, sNH, sNH, sNN, flagp);
    colsum64<<<dim3(N_/256, NB), blk, 0, stream>>>(P8, csg);
    // ---- PT = P^T (Tst dead now), then theta^2 via coalesced power iter ----
    transpose64<<<dim3(N_/32, N_/32, NB), blk, 0, stream>>>(P8, PTd);
    powiter<<<dim3(NB), dim3(512), 0, stream>>>(P8, PTd, csg, rex, th2, b0);
    // ---- S = L L^T + theta^2 I ----
    syrk64<<<g64, blk, 0, stream>>>(P8, csg, rex, th2, Md, b0, flagp);
    // ---- Sinv via scaled Newton: X' = 2g X - g^2 X (S X) ----
    newton_init<<<gEw, blk, 0, stream>>>(th2, Vd);
    for (int it = 0; it < J_NEWT; ++it) {
      const double* Xin  = (it & 1) ? C1d : Vd;
      double*       Xout = (it & 1) ? Vd : C1d;
      gemm_dd<0><<<g64, blk, 0, stream>>>(Md, Xin, Ctik, flagp, 0.0);       // T = S X
      gemm_dd<4><<<g64, blk, 0, stream>>>(Xin, Ctik, Xout, flagp, gam[it]); // X'
    }
    // J_NEWT=15: last it=14 (even) -> Sinv lands in C1d.
    // ---- C_tik = L^T Sinv ----
    linv64<<<g64, blk, 0, stream>>>(P8, csg, rex, C1d, Ctik, b0, flagp);
    // ---- Ghat = C_tik * L ; fused D = I - G and R0 = 2I - G ----
    ghat64<<<g64, blk, 0, stream>>>(Ctik, P8, csg, rex, Gd, Dd, Ra, b0, flagp);
    // ---- R = (I+D)(I+D^2)(I+D^4)(I+D^8)(I+D^16)  (deg-31) ----
    gemm_dd<0><<<g64, blk, 0, stream>>>(Dd, Dd, Rb, flagp, 0.0);   // D2
    gemm_dd<5><<<g64, blk, 0, stream>>>(Ra, Rb, C1d, flagp, 0.0);  // R *= (I+D2)
    gemm_dd<0><<<g64, blk, 0, stream>>>(Rb, Rb, Dd, flagp, 0.0);   // D4
    gemm_dd<5><<<g64, blk, 0, stream>>>(C1d, Dd, Ra, flagp, 0.0);  // R *= (I+D4)
    gemm_dd<0><<<g64, blk, 0, stream>>>(Dd, Dd, Rb, flagp, 0.0);   // D8
    gemm_dd<5><<<g64, blk, 0, stream>>>(Ra, Rb, C1d, flagp, 0.0);  // R *= (I+D8)
    gemm_dd<0><<<g64, blk, 0, stream>>>(Rb, Rb, Dd, flagp, 0.0);   // D16
    gemm_dd<5><<<g64, blk, 0, stream>>>(C1d, Dd, Ra, flagp, 0.0);  // R *= (I+D16)
    // ---- C1 = R * C_tik ----
    gemm_dd<0><<<g64, blk, 0, stream>>>(Ra, Ctik, C1d, flagp, 0.0);
    // ---- smoothstep^J on F = Ghat (ping Gd <-> Dd, T in Ra) ----
    double* F = Gd; double* Falt = Dd;
    for (int jit = 0; jit < J_SS; ++jit) {
      gemm_dd<0><<<g64, blk, 0, stream>>>(F, F, Ra, flagp, 0.0);    // T = F*F
      gemm_dd<2><<<g64, blk, 0, stream>>>(Ra, F, Falt, flagp, 0.0); // F' = 3T - 2TF
      double* tmp = F; F = Falt; Falt = tmp;
    }
    // ---- C_sharp = F * C1 ----
    gemm_dd<0><<<g64, blk, 0, stream>>>(F, C1d, Ctik, flagp, 0.0);
    // ---- A ----
    final64<<<g64, blk, 0, stream>>>(P8, Ctik, out + (size_t)b0 * sNN, flagp);
  }
}

// Round 23
// 31996.381 us; speedup vs baseline: 1.2354x; 1.2354x over previous
//
#include <hip/hip_runtime.h>
#include <math.h>

#define B_ 32
#define N_ 512
#define D_ 768
#define H_ 1024
#define NB 8             // batches per group
#define M8 (NB*N_)       // 4096 staging rows per group
#define J_SS 16          // smoothstep iterations (transition +-1.0%)
#define J_NEWT 15        // scaled-Newton iterations (residual ~1e-7)
#define POW_ITERS 60
// (jax f32 pinv rtol)^2 = (10 * 512 * 2^-23)^2
#define RTOL2 3.725290298461914e-7

typedef double dx4 __attribute__((ext_vector_type(4)));

// ---------------------------------------------------------------------------
#if __has_builtin(__builtin_amdgcn_mfma_f64_16x16x4f64)
__device__ __forceinline__ dx4 mfma64(double a, double b, dx4 c) {
  return __builtin_amdgcn_mfma_f64_16x16x4f64(a, b, c, 0, 0, 0);
}
#else
// No builtin: probe sees zeros -> flag=4 -> VALU path used everywhere.
__device__ __forceinline__ dx4 mfma64(double a, double b, dx4 c) { return c; }
#endif

// ---------------------------------------------------------------------------
// On-device MFMA D-layout probe (flag=4 -> VALU fallback).
// ---------------------------------------------------------------------------
__global__ __launch_bounds__(64) void mfma_probe(int* __restrict__ flag)
{
  const int l = threadIdx.x;
  const int lk = l >> 4;
  dx4 d1 = {}; d1 = mfma64((double)(l & 15), 1.0, d1);
  dx4 d2 = {}; d2 = mfma64(1.0, (double)(l & 15), d2);
  dx4 d3 = {}; d3 = mfma64((lk == 0) ? 1.0 : 0.0, (double)(lk + 1), d3);
  __shared__ double s1[256];
  __shared__ double s2[256];
  __shared__ double s3[256];
  #pragma unroll
  for (int e = 0; e < 4; ++e) { s1[l*4+e] = d1[e]; s2[l*4+e] = d2[e]; s3[l*4+e] = d3[e]; }
  __syncthreads();
  if (l == 0) {
    int f = 4;
    for (int c = 0; c < 4 && f == 4; ++c) {
      bool ok = true;
      for (int q = 0; q < 64 && ok; ++q) {
        for (int r = 0; r < 4 && ok; ++r) {
          int mi, ni;
          if (c == 0)      { mi = 4*(q>>4)+r; ni = q & 15; }
          else if (c == 1) { mi = (q>>4)+4*r; ni = q & 15; }
          else if (c == 2) { mi = q & 15; ni = 4*(q>>4)+r; }
          else             { mi = q & 15; ni = (q>>4)+4*r; }
          if (s1[q*4+r] != (double)(4*mi)) ok = false;
          if (s2[q*4+r] != (double)(4*ni)) ok = false;
          if (s3[q*4+r] != 1.0) ok = false;
        }
      }
      if (ok) f = c;
    }
    *flag = f;
  }
}

// ---------------------------------------------------------------------------
template<typename T>
__device__ inline void load4d(const T* __restrict__ p, double* d) {
  if constexpr (sizeof(T) == 4) {
    const float4 v = *(const float4*)p;
    d[0] = v.x; d[1] = v.y; d[2] = v.z; d[3] = v.w;
  } else {
    const double2 a = *(const double2*)p;
    const double2 b = *(const double2*)(p + 2);
    d[0] = a.x; d[1] = a.y; d[2] = b.x; d[3] = b.y;
  }
}

// ---------------------------------------------------------------------------
// Double-buffered GEMM driver, BK=16 (measured best, R18/R21 form).
// ld(k0, r): global -> regs (under previous chunk's compute).
// st(k0, r): regs -> LDS (with transforms).  epi(mi, ni, v): consume result.
// flagv 0..3 MFMA D-conv, 4 VALU fallback.
// ---------------------------------------------------------------------------
template<int NR, typename FLD, typename FST, typename FE>
__device__ __forceinline__ void run_gemm_db(int K, int flagv, int t,
    double (*As)[66], double (*Bs)[66], FLD ld, FST st, FE epi)
{
  const int lane = t & 63; const int wid = t >> 6;
  const int wr = (wid >> 1) << 5; const int wc = (wid & 1) << 5;
  const int lr = lane & 15; const int lk = lane >> 4;
  double r[NR];
  ld(0, r);
  if (flagv < 4) {
    dx4 acc[2][2] = {};
    for (int k0 = 0; k0 < K; k0 += 16) {
      __syncthreads();
      st(k0, r);
      __syncthreads();
      if (k0 + 16 < K) ld(k0 + 16, r);
      #pragma unroll
      for (int kq = 0; kq < 4; ++kq) {
        const int kr = (kq << 2) + lk;
        const double a0 = As[kr][wr + lr];
        const double a1 = As[kr][wr + 16 + lr];
        const double b0 = Bs[kr][wc + lr];
        const double b1 = Bs[kr][wc + 16 + lr];
        acc[0][0] = mfma64(a0, b0, acc[0][0]);
        acc[0][1] = mfma64(a0, b1, acc[0][1]);
        acc[1][0] = mfma64(a1, b0, acc[1][0]);
        acc[1][1] = mfma64(a1, b1, acc[1][1]);
      }
    }
    #pragma unroll
    for (int tm = 0; tm < 2; ++tm)
    #pragma unroll
    for (int tn = 0; tn < 2; ++tn)
    #pragma unroll
    for (int i = 0; i < 4; ++i) {
      int mo, no;
      if (flagv == 0)      { mo = (lk << 2) + i; no = lr; }
      else if (flagv == 1) { mo = lk + (i << 2); no = lr; }
      else if (flagv == 2) { mo = lr; no = (lk << 2) + i; }
      else                 { mo = lr; no = lk + (i << 2); }
      epi(wr + tm*16 + mo, wc + tn*16 + no, acc[tm][tn][i]);
    }
  } else {
    const int tx = t & 15, ty = t >> 4;
    double acc[4][4] = {};
    for (int k0 = 0; k0 < K; k0 += 16) {
      __syncthreads();
      st(k0, r);
      __syncthreads();
      if (k0 + 16 < K) ld(k0 + 16, r);
      #pragma unroll
      for (int kk = 0; kk < 16; ++kk) {
        double av[4], bv[4];
        #pragma unroll
        for (int q = 0; q < 4; ++q) { av[q] = As[kk][(ty<<2)+q]; bv[q] = Bs[kk][(tx<<2)+q]; }
        #pragma unroll
        for (int ii = 0; ii < 4; ++ii)
          #pragma unroll
          for (int jj = 0; jj < 4; ++jj)
            acc[ii][jj] = fma(av[ii], bv[jj], acc[ii][jj]);
      }
    }
    #pragma unroll
    for (int ii = 0; ii < 4; ++ii)
      #pragma unroll
      for (int jj = 0; jj < 4; ++jj)
        epi((ty << 2) + ii, (tx << 2) + jj, acc[ii][jj]);
  }
}

// Dual-accumulator double-buffered variant (final64): epi(mi, ni, vy, vz).
template<int NR, typename FLD, typename FST, typename FE>
__device__ __forceinline__ void run_gemm2_db(int K, int flagv, int t,
    double (*Ps)[66], double (*W1)[66], double (*W2)[66], FLD ld, FST st, FE epi)
{
  const int lane = t & 63; const int wid = t >> 6;
  const int wr = (wid >> 1) << 5; const int wc = (wid & 1) << 5;
  const int lr = lane & 15; const int lk = lane >> 4;
  double r[NR];
  ld(0, r);
  if (flagv < 4) {
    dx4 accY[2][2] = {};
    dx4 accZ[2][2] = {};
    for (int k0 = 0; k0 < K; k0 += 16) {
      __syncthreads();
      st(k0, r);
      __syncthreads();
      if (k0 + 16 < K) ld(k0 + 16, r);
      #pragma unroll
      for (int kq = 0; kq < 4; ++kq) {
        const int kr = (kq << 2) + lk;
        const double a0 = Ps[kr][wr + lr];
        const double a1 = Ps[kr][wr + 16 + lr];
        const double y0 = W1[kr][wc + lr];
        const double y1 = W1[kr][wc + 16 + lr];
        const double z0 = W2[kr][wc + lr];
        const double z1 = W2[kr][wc + 16 + lr];
        accY[0][0] = mfma64(a0, y0, accY[0][0]);
        accY[0][1] = mfma64(a0, y1, accY[0][1]);
        accY[1][0] = mfma64(a1, y0, accY[1][0]);
        accY[1][1] = mfma64(a1, y1, accY[1][1]);
        accZ[0][0] = mfma64(a0, z0, accZ[0][0]);
        accZ[0][1] = mfma64(a0, z1, accZ[0][1]);
        accZ[1][0] = mfma64(a1, z0, accZ[1][0]);
        accZ[1][1] = mfma64(a1, z1, accZ[1][1]);
      }
    }
    #pragma unroll
    for (int tm = 0; tm < 2; ++tm)
    #pragma unroll
    for (int tn = 0; tn < 2; ++tn)
    #pragma unroll
    for (int i = 0; i < 4; ++i) {
      int mo, no;
      if (flagv == 0)      { mo = (lk << 2) + i; no = lr; }
      else if (flagv == 1) { mo = lk + (i << 2); no = lr; }
      else if (flagv == 2) { mo = lr; no = (lk << 2) + i; }
      else                 { mo = lr; no = lk + (i << 2); }
      epi(wr + tm*16 + mo, wc + tn*16 + no, accY[tm][tn][i], accZ[tm][tn][i]);
    }
  } else {
    const int tx = t & 15, ty = t >> 4;
    double aY[4][4] = {};
    double aZ[4][4] = {};
    for (int k0 = 0; k0 < K; k0 += 16) {
      __syncthreads();
      st(k0, r);
      __syncthreads();
      if (k0 + 16 < K) ld(k0 + 16, r);
      #pragma unroll
      for (int kk = 0; kk < 16; ++kk) {
        double av[4], y[4], z[4];
        #pragma unroll
        for (int q = 0; q < 4; ++q) {
          av[q] = Ps[kk][(ty<<2)+q]; y[q] = W1[kk][(tx<<2)+q]; z[q] = W2[kk][(tx<<2)+q];
        }
        #pragma unroll
        for (int ii = 0; ii < 4; ++ii)
          #pragma unroll
          for (int jj = 0; jj < 4; ++jj) {
            aY[ii][jj] = fma(av[ii], y[jj], aY[ii][jj]);
            aZ[ii][jj] = fma(av[ii], z[jj], aZ[ii][jj]);
          }
      }
    }
    #pragma unroll
    for (int ii = 0; ii < 4; ++ii)
      #pragma unroll
      for (int jj = 0; jj < 4; ++jj)
        epi((ty << 2) + ii, (tx << 2) + jj, aY[ii][jj], aZ[ii][jj]);
  }
}

// ---------------------------------------------------------------------------
// f64 tiled GEMM, mixed input types, f64 output.
// EPI: 0 none; 1 tanh(v + bias[n]); 2 (m==n ? 0 : exp(v))
// ---------------------------------------------------------------------------
template<typename TA, typename TB, int TRANSB, int EPI>
__global__ __launch_bounds__(256) void gemm64(
    const TA* __restrict__ A, const TB* __restrict__ Bm,
    const float* __restrict__ bias, double* __restrict__ C,
    int M, int Nn, int K, size_t sA, size_t sB, size_t sC,
    const int* __restrict__ flagp)
{
  A  += (size_t)blockIdx.z * sA;
  Bm += (size_t)blockIdx.z * sB;
  C  += (size_t)blockIdx.z * sC;
  __shared__ double As[16][66];
  __shared__ double Bs[16][66];
  const int t  = threadIdx.x;
  const int m0 = blockIdx.y * 64, n0 = blockIdx.x * 64;
  const int flagv = *flagp;
  auto ld = [&](int k0, double* r) {
    const int ml = t >> 2; const int kc = (t & 3) << 2;
    load4d(A + (size_t)(m0 + ml) * K + k0 + kc, r);
    if (TRANSB) {
      const int nl = t >> 2;
      load4d(Bm + (size_t)(n0 + nl) * K + k0 + kc, r + 4);
    } else {
      const int kl = t >> 4; const int nc = (t & 15) << 2;
      load4d(Bm + (size_t)(k0 + kl) * Nn + n0 + nc, r + 4);
    }
  };
  auto st = [&](int k0, double* r) {
    const int ml = t >> 2; const int kc = (t & 3) << 2;
    #pragma unroll
    for (int q = 0; q < 4; ++q) As[kc+q][ml] = r[q];
    if (TRANSB) {
      const int nl = t >> 2;
      #pragma unroll
      for (int q = 0; q < 4; ++q) Bs[kc+q][nl] = r[4+q];
    } else {
      const int kl = t >> 4; const int nc = (t & 15) << 2;
      #pragma unroll
      for (int q = 0; q < 4; ++q) Bs[kl][nc+q] = r[4+q];
    }
  };
  auto epi = [&](int mi, int ni, double v) {
    const int m = m0 + mi; const int n = n0 + ni;
    if constexpr (EPI == 1) v = tanh(v + (double)bias[n]);
    if constexpr (EPI == 2) v = (m == n) ? 0.0 : exp(v);
    C[(size_t)m * Nn + n] = v;
  };
  run_gemm_db<8>(K, flagv, t, As, Bs, ld, st, epi);
}

// ---------------------------------------------------------------------------
__global__ __launch_bounds__(256) void rexp_kernel(
    const float* __restrict__ x, const float* __restrict__ WR,
    const float* __restrict__ bR, double* __restrict__ rex)
{
  const int b = blockIdx.x, t = threadIdx.x;
  const float* xb = x + (size_t)b * N_ * D_;
  double s = 0.0;
  for (int d = t; d < D_; d += 256) s += (double)xb[d] * (double)WR[d];
  __shared__ double sm[256];
  sm[t] = s; __syncthreads();
  for (int o = 128; o > 0; o >>= 1) { if (t < o) sm[t] += sm[t + o]; __syncthreads(); }
  if (t == 0) rex[b] = exp(sm[0] + (double)bR[0]);
}

// ---------------------------------------------------------------------------
__global__ __launch_bounds__(256) void colsum64(
    const double* __restrict__ P, double* __restrict__ cs)
{
  const int bl = blockIdx.y;
  const int j = blockIdx.x * 256 + threadIdx.x;
  const double* Pb = P + (size_t)bl * N_ * N_;
  double s0 = 0.0, s1 = 0.0, s2 = 0.0, s3 = 0.0;
  for (int i = 0; i < N_; i += 4) {
    s0 += Pb[(size_t)(i+0) * N_ + j];
    s1 += Pb[(size_t)(i+1) * N_ + j];
    s2 += Pb[(size_t)(i+2) * N_ + j];
    s3 += Pb[(size_t)(i+3) * N_ + j];
  }
  cs[bl * N_ + j] = (s0 + s1) + (s2 + s3);
}

// ---------------------------------------------------------------------------
// PT = P^T (per batch), 32x32 LDS tiles. PT[k][i] = P[i][k].
// ---------------------------------------------------------------------------
__global__ __launch_bounds__(256) void transpose64(
    const double* __restrict__ P, double* __restrict__ PT)
{
  __shared__ double tile[32][33];
  const int bl = blockIdx.z;
  const double* Pb = P + (size_t)bl * N_ * N_;
  double* Tb = PT + (size_t)bl * N_ * N_;
  const int x0 = blockIdx.x * 32, y0 = blockIdx.y * 32;
  const int tx = threadIdx.x & 31, ty = threadIdx.x >> 5;   // 32 x 8
  #pragma unroll
  for (int r = 0; r < 32; r += 8)
    tile[ty + r][tx] = Pb[(size_t)(y0 + ty + r) * N_ + x0 + tx];
  __syncthreads();
  #pragma unroll
  for (int r = 0; r < 32; r += 8)
    Tb[(size_t)(x0 + ty + r) * N_ + y0 + tx] = tile[tx][ty + r];
}

// ---------------------------------------------------------------------------
// Power iteration on L^T L (virtual L) -> theta2[bl] = RTOL2 * sigma_max^2
// ---------------------------------------------------------------------------
__global__ __launch_bounds__(512) void powiter(
    const double* __restrict__ P, const double* __restrict__ PT,
    const double* __restrict__ cs, const double* __restrict__ rex,
    double* __restrict__ theta2, int b0)
{
  const int bl = blockIdx.x, t = threadIdx.x;
  const double* Pb  = P  + (size_t)bl * N_ * N_;
  const double* PTb = PT + (size_t)bl * N_ * N_;
  const double* csb = cs + (size_t)bl * N_;
  const double rx = rex[b0 + bl];
  __shared__ double v[N_], y[N_], red[512];
  v[t] = 1.0; __syncthreads();
  double sig2 = 0.0;
  for (int it = 0; it < POW_ITERS; ++it) {
    red[t] = v[t]; __syncthreads();
    for (int o = 256; o > 0; o >>= 1) { if (t < o) red[t] += red[t+o]; __syncthreads(); }
    const double sumv = red[0];
    double s;
    if (t == 0) s = rx * sumv;
    else {
      s = csb[t] * v[t];
      double d0 = 0.0, d1 = 0.0, d2 = 0.0, d3 = 0.0;
      for (int k = 0; k < N_; k += 4) {
        d0 += PTb[(size_t)(k+0) * N_ + t] * v[k+0];
        d1 += PTb[(size_t)(k+1) * N_ + t] * v[k+1];
        d2 += PTb[(size_t)(k+2) * N_ + t] * v[k+2];
        d3 += PTb[(size_t)(k+3) * N_ + t] * v[k+3];
      }
      s -= (d0 + d1) + (d2 + d3);
    }
    __syncthreads();
    y[t] = s; __syncthreads();
    const double y0 = y[0];
    double z = rx * y0 + ((t > 0) ? csb[t] * y[t] : 0.0) + Pb[t] * y0;
    {
      double d0 = 0.0, d1 = 0.0, d2 = 0.0, d3 = 0.0;
      for (int i = 0; i < N_; i += 4) {
        d0 += Pb[(size_t)(i+0) * N_ + t] * y[i+0];
        d1 += Pb[(size_t)(i+1) * N_ + t] * y[i+1];
        d2 += Pb[(size_t)(i+2) * N_ + t] * y[i+2];
        d3 += Pb[(size_t)(i+3) * N_ + t] * y[i+3];
      }
      z -= (d0 + d1) + (d2 + d3);
    }
    red[t] = z * z; __syncthreads();
    for (int o = 256; o > 0; o >>= 1) { if (t < o) red[t] += red[t+o]; __syncthreads(); }
    const double nz = sqrt(red[0]);
    sig2 = nz;
    v[t] = z / nz; __syncthreads();
  }
  if (t == 0) theta2[bl] = RTOL2 * sig2;
}

// ---------------------------------------------------------------------------
// S = L L^T + theta2 * I   (virtual L)
// ---------------------------------------------------------------------------
__global__ __launch_bounds__(256) void syrk64(
    const double* __restrict__ P, const double* __restrict__ cs,
    const double* __restrict__ rex, const double* __restrict__ th2,
    double* __restrict__ S, int b0, const int* __restrict__ flagp)
{
  const int bl = blockIdx.z;
  const double* Pb  = P + (size_t)bl * N_ * N_;
  const double* csb = cs + (size_t)bl * N_;
  const double rx = rex[b0 + bl];
  double* Sb = S + (size_t)bl * N_ * N_;
  __shared__ double As[16][66];
  __shared__ double Bs[16][66];
  const int t  = threadIdx.x;
  const int i0 = blockIdx.y * 64, j0 = blockIdx.x * 64;
  const int flagv = *flagp;
  const double l2 = th2[bl];
  auto ld = [&](int k0, double* r) {
    const int ml = t >> 2; const int kc = (t & 3) << 2;
    load4d(Pb + (size_t)(i0 + ml) * N_ + k0 + kc, r);
    load4d(Pb + (size_t)(j0 + ml) * N_ + k0 + kc, r + 4);
  };
  auto st = [&](int k0, double* r) {
    const int ml = t >> 2; const int kc = (t & 3) << 2;
    const int i = i0 + ml;
    #pragma unroll
    for (int q = 0; q < 4; ++q) {
      const int k = k0 + kc + q;
      As[kc+q][ml] = (i == 0) ? rx : ((i == k) ? csb[k] : -r[q]);
    }
    const int j = j0 + ml;
    #pragma unroll
    for (int q = 0; q < 4; ++q) {
      const int k = k0 + kc + q;
      Bs[kc+q][ml] = (j == 0) ? rx : ((j == k) ? csb[k] : -r[4+q]);
    }
  };
  auto epi = [&](int mi, int ni, double v) {
    const int ig = i0 + mi; const int jg = j0 + ni;
    if (ig == jg) v += l2;
    Sb[(size_t)ig * N_ + jg] = v;
  };
  run_gemm_db<8>(N_, flagv, t, As, Bs, ld, st, epi);
}

// ---------------------------------------------------------------------------
// Newton init: X0 = I / (1.1 * lambda_max),  lambda_max = th2*(1+RTOL2)/RTOL2.
// ---------------------------------------------------------------------------
__global__ __launch_bounds__(256) void newton_init(
    const double* __restrict__ th2, double* __restrict__ X)
{
  const size_t idx = (size_t)blockIdx.x * 256 + threadIdx.x;
  const int bl  = (int)(idx >> 18);
  const int rem = (int)(idx & ((size_t)N_ * N_ - 1));
  const double c = RTOL2 / (1.1 * th2[bl] * (1.0 + RTOL2));
  X[idx] = ((rem >> 9) == (rem & (N_ - 1))) ? c : 0.0;
}

// ---------------------------------------------------------------------------
// Ctik[i,j] = sum_k L[k,i] * Sinv[k,j]   (Ctik = L^T Sinv, virtual L)
// ---------------------------------------------------------------------------
__global__ __launch_bounds__(256) void linv64(
    const double* __restrict__ P, const double* __restrict__ cs,
    const double* __restrict__ rex, const double* __restrict__ Sinv,
    double* __restrict__ Out, int b0, const int* __restrict__ flagp)
{
  const int bl = blockIdx.z;
  const double* Pb  = P + (size_t)bl * N_ * N_;
  const double* csb = cs + (size_t)bl * N_;
  const double rx = rex[b0 + bl];
  const double* Sb = Sinv + (size_t)bl * N_ * N_;
  double* Ob = Out + (size_t)bl * N_ * N_;
  __shared__ double As[16][66];   // [k][i] = L[k0+k][i0+i]
  __shared__ double Bs[16][66];   // [k][j] = Sinv[k0+k][j0+j]
  const int t  = threadIdx.x;
  const int i0 = blockIdx.y * 64, j0 = blockIdx.x * 64;
  const int flagv = *flagp;
  auto ld = [&](int k0, double* r) {
    const int kl = t >> 4; const int c4 = (t & 15) << 2;
    const int k = k0 + kl;
    load4d(Pb + (size_t)k * N_ + i0 + c4, r);
    load4d(Sb + (size_t)k * N_ + j0 + c4, r + 4);
  };
  auto st = [&](int k0, double* r) {
    const int kl = t >> 4; const int c4 = (t & 15) << 2;
    const int k = k0 + kl;
    #pragma unroll
    for (int q = 0; q < 4; ++q) {
      const int i = i0 + c4 + q;
      As[kl][c4+q] = (k == 0) ? rx : ((k == i) ? csb[k] : -r[q]);
    }
    #pragma unroll
    for (int q = 0; q < 4; ++q) Bs[kl][c4+q] = r[4+q];
  };
  auto epi = [&](int mi, int ni, double v) {
    Ob[(size_t)(i0 + mi) * N_ + j0 + ni] = v;
  };
  run_gemm_db<8>(N_, flagv, t, As, Bs, ld, st, epi);
}

// ---------------------------------------------------------------------------
// Ghat = A * L_virtual.  Fused epilogue also emits D = I - G and R0 = 2I - G.
// ---------------------------------------------------------------------------
__global__ __launch_bounds__(256) void ghat64(
    const double* __restrict__ A, const double* __restrict__ P,
    const double* __restrict__ cs, const double* __restrict__ rex,
    double* __restrict__ OutG, double* __restrict__ OutD,
    double* __restrict__ OutR, int b0, const int* __restrict__ flagp)
{
  const int bl = blockIdx.z;
  const double* Ab  = A + (size_t)bl * N_ * N_;
  const double* Pb  = P + (size_t)bl * N_ * N_;
  const double* csb = cs + (size_t)bl * N_;
  const double rx = rex[b0 + bl];
  double* Gb = OutG + (size_t)bl * N_ * N_;
  double* Db = OutD + (size_t)bl * N_ * N_;
  double* Rb = OutR + (size_t)bl * N_ * N_;
  __shared__ double As[16][66];
  __shared__ double Bs[16][66];
  const int t  = threadIdx.x;
  const int m0 = blockIdx.y * 64, n0 = blockIdx.x * 64;
  const int flagv = *flagp;
  auto ld = [&](int k0, double* r) {
    const int ml = t >> 2; const int kc = (t & 3) << 2;
    load4d(Ab + (size_t)(m0 + ml) * N_ + k0 + kc, r);
    const int kl = t >> 4; const int nc = (t & 15) << 2;
    load4d(Pb + (size_t)(k0 + kl) * N_ + n0 + nc, r + 4);
  };
  auto st = [&](int k0, double* r) {
    const int ml = t >> 2; const int kc = (t & 3) << 2;
    #pragma unroll
    for (int q = 0; q < 4; ++q) As[kc+q][ml] = r[q];
    const int kl = t >> 4; const int nc = (t & 15) << 2;
    const int k = k0 + kl;
    #pragma unroll
    for (int q = 0; q < 4; ++q) {
      const int n = n0 + nc + q;
      Bs[kl][nc+q] = (k == 0) ? rx : ((k == n) ? csb[k] : -r[4+q]);
    }
  };
  auto epi = [&](int mi, int ni, double v) {
    const int m = m0 + mi; const int n = n0 + ni;
    const double di = (m == n) ? 1.0 : 0.0;
    const size_t off = (size_t)m * N_ + n;
    Gb[off] = v;
    Db[off] = di - v;         // D = I - G
    Rb[off] = 2.0 * di - v;   // R0 = 2I - G
  };
  run_gemm_db<8>(N_, flagv, t, As, Bs, ld, st, epi);
}

// ---------------------------------------------------------------------------
// f64 NN GEMM (batched stride N*N), full grid.
// EPI 0: C = A*B.               EPI 2: C = 3*A - 2*A*B  (smoothstep).
// EPI 4: C = 2g*A - g^2*A*B     (scaled Newton, g runtime).
// EPI 5: C = A + A*B            (Horner product accumulate).
// ---------------------------------------------------------------------------
template<int EPI>
__global__ __launch_bounds__(256) void gemm_dd(
    const double* __restrict__ A, const double* __restrict__ Bm,
    double* __restrict__ C, const int* __restrict__ flagp, double g)
{
  const size_t s = (size_t)N_ * N_;
  const double* Ab = A  + (size_t)blockIdx.z * s;
  const double* Bb = Bm + (size_t)blockIdx.z * s;
  double*       Cb = C  + (size_t)blockIdx.z * s;
  __shared__ double As[16][66];
  __shared__ double Bs[16][66];
  const int t  = threadIdx.x;
  const int m0 = blockIdx.y * 64, n0 = blockIdx.x * 64;
  const int flagv = *flagp;
  auto ld = [&](int k0, double* r) {
    const int ml = t >> 2; const int kc = (t & 3) << 2;
    load4d(Ab + (size_t)(m0 + ml) * N_ + k0 + kc, r);
    const int kl = t >> 4; const int nc = (t & 15) << 2;
    load4d(Bb + (size_t)(k0 + kl) * N_ + n0 + nc, r + 4);
  };
  auto st = [&](int k0, double* r) {
    const int ml = t >> 2; const int kc = (t & 3) << 2;
    #pragma unroll
    for (int q = 0; q < 4; ++q) As[kc+q][ml] = r[q];
    const int kl = t >> 4; const int nc = (t & 15) << 2;
    #pragma unroll
    for (int q = 0; q < 4; ++q) Bs[kl][nc+q] = r[4+q];
  };
  auto epi = [&](int mi, int ni, double v) {
    const int m = m0 + mi; const int n = n0 + ni;
    if constexpr (EPI == 2) v = 3.0 * Ab[(size_t)m * N_ + n] - 2.0 * v;
    if constexpr (EPI == 4) v = 2.0 * g * Ab[(size_t)m * N_ + n] - g * g * v;
    if constexpr (EPI == 5) v = Ab[(size_t)m * N_ + n] + v;
    Cb[(size_t)m * N_ + n] = v;
  };
  run_gemm_db<8>(N_, flagv, t, As, Bs, ld, st, epi);
}

// ---------------------------------------------------------------------------
// out[bl,i,j] = (j>0)*(P @ C)[i,j] - (i>0)*(P @ C^T)[i,j]
// ---------------------------------------------------------------------------
__global__ __launch_bounds__(256) void final64(
    const double* __restrict__ P, const double* __restrict__ X,
    float* __restrict__ Out, const int* __restrict__ flagp)
{
  const int bl = blockIdx.z;
  const double* Pb = P + (size_t)bl * N_ * N_;
  const double* Ib = X + (size_t)bl * N_ * N_;
  float*        Ob = Out + (size_t)bl * N_ * N_;
  __shared__ double Ps[16][66];
  __shared__ double W1[16][66];
  __shared__ double W2[16][66];
  const int t  = threadIdx.x;
  const int m0 = blockIdx.y * 64, n0 = blockIdx.x * 64;
  const int flagv = *flagp;
  auto ld = [&](int k0, double* r) {
    const int ml = t >> 2; const int kc = (t & 3) << 2;
    load4d(Pb + (size_t)(m0 + ml) * N_ + k0 + kc, r);
    load4d(Ib + (size_t)(n0 + ml) * N_ + k0 + kc, r + 4);
    const int kl = t >> 4; const int nc = (t & 15) << 2;
    load4d(Ib + (size_t)(k0 + kl) * N_ + n0 + nc, r + 8);
  };
  auto st = [&](int k0, double* r) {
    const int ml = t >> 2; const int kc = (t & 3) << 2;
    #pragma unroll
    for (int q = 0; q < 4; ++q) Ps[kc+q][ml] = r[q];
    #pragma unroll
    for (int q = 0; q < 4; ++q) W2[kc+q][ml] = r[4+q];
    const int kl = t >> 4; const int nc = (t & 15) << 2;
    #pragma unroll
    for (int q = 0; q < 4; ++q) W1[kl][nc+q] = r[8+q];
  };
  auto epi = [&](int mi, int ni, double vy, double vz) {
    const int m = m0 + mi; const int n = n0 + ni;
    double v = 0.0;
    if (n > 0) v += vy;
    if (m > 0) v -= vz;
    Ob[(size_t)m * N_ + n] = (float)v;
  };
  run_gemm2_db<12>(N_, flagv, t, Ps, W1, W2, ld, st, epi);
}

// ---------------------------------------------------------------------------
extern "C" void kernel_launch(void* const* d_in, const int* in_sizes, int n_in,
                              void* d_out, int out_size, void* d_ws, size_t ws_size,
                              hipStream_t stream)
{
  const float* x    = (const float*)d_in[0];
  const float* W_P  = (const float*)d_in[1];
  const float* b_P  = (const float*)d_in[2];
  const float* W_C  = (const float*)d_in[3];
  const float* b_C  = (const float*)d_in[4];
  const float* W_bl = (const float*)d_in[5];
  const float* W_R  = (const float*)d_in[6];
  const float* b_R  = (const float*)d_in[7];
  float* out = (float*)d_out;
  char*  ws8 = (char*)d_ws;

  // Workspace (bytes), peak ~144.1 MB:
  double* encS = (double*)(ws8 + 0);           // 32 MB encP/encC -> Gd, Dd
  double* Tst  = (double*)(ws8 + 33554432);    // 32 MB T8 -> PT -> Ra, Rb
  double* P8   = (double*)(ws8 + 67108864);    // 16 MB
  double* Md   = (double*)(ws8 + 83886080);    // 16 MB S (const through Newton)
  double* Vd   = (double*)(ws8 + 100663296);   // 16 MB X ping
  double* Ctik = (double*)(ws8 + 117440512);   // 16 MB T temp -> Ctik
  double* C1d  = (double*)(ws8 + 134217728);   // 16 MB X pong (ends=Sinv) -> C1
  double* csg  = (double*)(ws8 + 150994944);   // 32 KB
  double* th2  = (double*)(ws8 + 151027712);   // 64 B
  double* rex  = (double*)(ws8 + 151027776);   // 256 B
  int*    flagp= (int*)   (ws8 + 151028032);   // 4 B : MFMA layout flag
  double* Gd   = (double*)(ws8 + 0);
  double* Dd   = (double*)(ws8 + 16777216);
  double* Ra   = (double*)(ws8 + 33554432);
  double* Rb   = (double*)(ws8 + 50331648);
  double* PTd  = (double*)(ws8 + 33554432);    // PT aliases Tst/Ra (dead then)

  // Host-computed scaled-Newton gamma schedule (data-independent).
  double gam[J_NEWT];
  {
    double a = RTOL2 / (1.1 * (1.0 + RTOL2));
    double b = (1.0 / 1.1) * 1.08;
    for (int k = 0; k < J_NEWT; ++k) {
      double g = 2.0 / (a + b);
      if (g < 1.0) g = 1.0;
      gam[k] = g;
      double ga = g * a;
      a = ga * (2.0 - ga);
      if (a > 1.0) a = 1.0;
      b = 1.0;
    }
  }

  const dim3 blk(256);
  const size_t sNH = (size_t)N_ * H_;
  const size_t sNN = (size_t)N_ * N_;
  const dim3 g64(N_/64, N_/64, NB);
  const dim3 gEw((NB * N_ * N_) / 256);

  // On-device MFMA D-layout probe (4 conventions + VALU fallback).
  mfma_probe<<<dim3(1), dim3(64), 0, stream>>>(flagp);
  rexp_kernel<<<dim3(B_), blk, 0, stream>>>(x, W_R, b_R, rex);

  for (int g = 0; g < 4; ++g) {
    const int b0 = g * NB;
    const float* xg = x + (size_t)b0 * N_ * D_;
    // ---- upstream (f64) ----
    gemm64<float,float,1,1><<<dim3(H_/64, M8/64, 1), blk, 0, stream>>>(
        xg, W_P, b_P, encS, M8, H_, D_, 0, 0, 0, flagp);
    gemm64<double,float,0,0><<<dim3(H_/64, M8/64, 1), blk, 0, stream>>>(
        encS, W_bl, nullptr, Tst, M8, H_, H_, 0, 0, 0, flagp);
    gemm64<float,float,1,1><<<dim3(H_/64, M8/64, 1), blk, 0, stream>>>(
        xg, W_C, b_C, encS, M8, H_, D_, 0, 0, 0, flagp);
    gemm64<double,double,1,2><<<g64, blk, 0, stream>>>(
        Tst, encS, nullptr, P8, N_, N_, H_, sNH, sNH, sNN, flagp);
    colsum64<<<dim3(N_/256, NB), blk, 0, stream>>>(P8, csg);
    // ---- PT = P^T (Tst dead now), then theta^2 via coalesced power iter ----
    transpose64<<<dim3(N_/32, N_/32, NB), blk, 0, stream>>>(P8, PTd);
    powiter<<<dim3(NB), dim3(512), 0, stream>>>(P8, PTd, csg, rex, th2, b0);
    // ---- S = L L^T + theta^2 I ----
    syrk64<<<g64, blk, 0, stream>>>(P8, csg, rex, th2, Md, b0, flagp);
    // ---- Sinv via scaled Newton: X' = 2g X - g^2 X (S X) ----
    newton_init<<<gEw, blk, 0, stream>>>(th2, Vd);
    for (int it = 0; it < J_NEWT; ++it) {
      const double* Xin  = (it & 1) ? C1d : Vd;
      double*       Xout = (it & 1) ? Vd : C1d;
      gemm_dd<0><<<g64, blk, 0, stream>>>(Md, Xin, Ctik, flagp, 0.0);       // T = S X
      gemm_dd<4><<<g64, blk, 0, stream>>>(Xin, Ctik, Xout, flagp, gam[it]); // X'
    }
    // J_NEWT=15: last it=14 (even) -> Sinv lands in C1d.
    // ---- C_tik = L^T Sinv ----
    linv64<<<g64, blk, 0, stream>>>(P8, csg, rex, C1d, Ctik, b0, flagp);
    // ---- Ghat = C_tik * L ; fused D = I - G and R0 = 2I - G ----
    ghat64<<<g64, blk, 0, stream>>>(Ctik, P8, csg, rex, Gd, Dd, Ra, b0, flagp);
    // ---- R = (I+D)(I+D^2)(I+D^4)(I+D^8)(I+D^16)  (deg-31) ----
    gemm_dd<0><<<g64, blk, 0, stream>>>(Dd, Dd, Rb, flagp, 0.0);   // D2
    gemm_dd<5><<<g64, blk, 0, stream>>>(Ra, Rb, C1d, flagp, 0.0);  // R *= (I+D2)
    gemm_dd<0><<<g64, blk, 0, stream>>>(Rb, Rb, Dd, flagp, 0.0);   // D4
    gemm_dd<5><<<g64, blk, 0, stream>>>(C1d, Dd, Ra, flagp, 0.0);  // R *= (I+D4)
    gemm_dd<0><<<g64, blk, 0, stream>>>(Dd, Dd, Rb, flagp, 0.0);   // D8
    gemm_dd<5><<<g64, blk, 0, stream>>>(Ra, Rb, C1d, flagp, 0.0);  // R *= (I+D8)
    gemm_dd<0><<<g64, blk, 0, stream>>>(Rb, Rb, Dd, flagp, 0.0);   // D16
    gemm_dd<5><<<g64, blk, 0, stream>>>(C1d, Dd, Ra, flagp, 0.0);  // R *= (I+D16)
    // ---- C1 = R * C_tik ----
    gemm_dd<0><<<g64, blk, 0, stream>>>(Ra, Ctik, C1d, flagp, 0.0);
    // ---- smoothstep^J on F = Ghat (ping Gd <-> Dd, T in Ra) ----
    double* F = Gd; double* Falt = Dd;
    for (int jit = 0; jit < J_SS; ++jit) {
      gemm_dd<0><<<g64, blk, 0, stream>>>(F, F, Ra, flagp, 0.0);    // T = F*F
      gemm_dd<2><<<g64, blk, 0, stream>>>(Ra, F, Falt, flagp, 0.0); // F' = 3T - 2TF
      double* tmp = F; F = Falt; Falt = tmp;
    }
    // ---- C_sharp = F * C1 ----
    gemm_dd<0><<<g64, blk, 0, stream>>>(F, C1d, Ctik, flagp, 0.0);
    // ---- A ----
    final64<<<g64, blk, 0, stream>>>(P8, Ctik, out + (size_t)b0 * sNN, flagp);
  }
}

// Round 24
// 24201.093 us; speedup vs baseline: 1.6333x; 1.3221x over previous
//
#include <hip/hip_runtime.h>
#include <math.h>

#define B_ 32
#define N_ 512
#define D_ 768
#define H_ 1024
#define NB 8             // batches per group
#define M8 (NB*N_)       // 4096 staging rows per group
#define J_SS 16          // smoothstep iterations (transition +-1.0%)
#define J_NEWT 15        // scaled-Newton iterations (residual ~1e-7)
#define POW_ITERS 30
// (jax f32 pinv rtol)^2 = (10 * 512 * 2^-23)^2
#define RTOL2 3.725290298461914e-7

typedef double dx4 __attribute__((ext_vector_type(4)));

// ---------------------------------------------------------------------------
#if __has_builtin(__builtin_amdgcn_mfma_f64_16x16x4f64)
__device__ __forceinline__ dx4 mfma64(double a, double b, dx4 c) {
  return __builtin_amdgcn_mfma_f64_16x16x4f64(a, b, c, 0, 0, 0);
}
#else
// No builtin: probe sees zeros -> flag=4 -> VALU path used everywhere.
__device__ __forceinline__ dx4 mfma64(double a, double b, dx4 c) { return c; }
#endif

// ---------------------------------------------------------------------------
// On-device MFMA D-layout probe (flag=4 -> VALU fallback).
// ---------------------------------------------------------------------------
__global__ __launch_bounds__(64) void mfma_probe(int* __restrict__ flag)
{
  const int l = threadIdx.x;
  const int lk = l >> 4;
  dx4 d1 = {}; d1 = mfma64((double)(l & 15), 1.0, d1);
  dx4 d2 = {}; d2 = mfma64(1.0, (double)(l & 15), d2);
  dx4 d3 = {}; d3 = mfma64((lk == 0) ? 1.0 : 0.0, (double)(lk + 1), d3);
  __shared__ double s1[256];
  __shared__ double s2[256];
  __shared__ double s3[256];
  #pragma unroll
  for (int e = 0; e < 4; ++e) { s1[l*4+e] = d1[e]; s2[l*4+e] = d2[e]; s3[l*4+e] = d3[e]; }
  __syncthreads();
  if (l == 0) {
    int f = 4;
    for (int c = 0; c < 4 && f == 4; ++c) {
      bool ok = true;
      for (int q = 0; q < 64 && ok; ++q) {
        for (int r = 0; r < 4 && ok; ++r) {
          int mi, ni;
          if (c == 0)      { mi = 4*(q>>4)+r; ni = q & 15; }
          else if (c == 1) { mi = (q>>4)+4*r; ni = q & 15; }
          else if (c == 2) { mi = q & 15; ni = 4*(q>>4)+r; }
          else             { mi = q & 15; ni = (q>>4)+4*r; }
          if (s1[q*4+r] != (double)(4*mi)) ok = false;
          if (s2[q*4+r] != (double)(4*ni)) ok = false;
          if (s3[q*4+r] != 1.0) ok = false;
        }
      }
      if (ok) f = c;
    }
    *flag = f;
  }
}

// ---------------------------------------------------------------------------
template<typename T>
__device__ inline void load4d(const T* __restrict__ p, double* d) {
  if constexpr (sizeof(T) == 4) {
    const float4 v = *(const float4*)p;
    d[0] = v.x; d[1] = v.y; d[2] = v.z; d[3] = v.w;
  } else {
    const double2 a = *(const double2*)p;
    const double2 b = *(const double2*)(p + 2);
    d[0] = a.x; d[1] = a.y; d[2] = b.x; d[3] = b.y;
  }
}

// ---------------------------------------------------------------------------
// Double-buffered GEMM driver, BK=16 (measured best, R18/R21/R23 form).
// ld(k0, r): global -> regs (under previous chunk's compute).
// st(k0, r): regs -> LDS (with transforms).  epi(mi, ni, v): consume result.
// flagv 0..3 MFMA D-conv, 4 VALU fallback.
// ---------------------------------------------------------------------------
template<int NR, typename FLD, typename FST, typename FE>
__device__ __forceinline__ void run_gemm_db(int K, int flagv, int t,
    double (*As)[66], double (*Bs)[66], FLD ld, FST st, FE epi)
{
  const int lane = t & 63; const int wid = t >> 6;
  const int wr = (wid >> 1) << 5; const int wc = (wid & 1) << 5;
  const int lr = lane & 15; const int lk = lane >> 4;
  double r[NR];
  ld(0, r);
  if (flagv < 4) {
    dx4 acc[2][2] = {};
    for (int k0 = 0; k0 < K; k0 += 16) {
      __syncthreads();
      st(k0, r);
      __syncthreads();
      if (k0 + 16 < K) ld(k0 + 16, r);
      #pragma unroll
      for (int kq = 0; kq < 4; ++kq) {
        const int kr = (kq << 2) + lk;
        const double a0 = As[kr][wr + lr];
        const double a1 = As[kr][wr + 16 + lr];
        const double b0 = Bs[kr][wc + lr];
        const double b1 = Bs[kr][wc + 16 + lr];
        acc[0][0] = mfma64(a0, b0, acc[0][0]);
        acc[0][1] = mfma64(a0, b1, acc[0][1]);
        acc[1][0] = mfma64(a1, b0, acc[1][0]);
        acc[1][1] = mfma64(a1, b1, acc[1][1]);
      }
    }
    #pragma unroll
    for (int tm = 0; tm < 2; ++tm)
    #pragma unroll
    for (int tn = 0; tn < 2; ++tn)
    #pragma unroll
    for (int i = 0; i < 4; ++i) {
      int mo, no;
      if (flagv == 0)      { mo = (lk << 2) + i; no = lr; }
      else if (flagv == 1) { mo = lk + (i << 2); no = lr; }
      else if (flagv == 2) { mo = lr; no = (lk << 2) + i; }
      else                 { mo = lr; no = lk + (i << 2); }
      epi(wr + tm*16 + mo, wc + tn*16 + no, acc[tm][tn][i]);
    }
  } else {
    const int tx = t & 15, ty = t >> 4;
    double acc[4][4] = {};
    for (int k0 = 0; k0 < K; k0 += 16) {
      __syncthreads();
      st(k0, r);
      __syncthreads();
      if (k0 + 16 < K) ld(k0 + 16, r);
      #pragma unroll
      for (int kk = 0; kk < 16; ++kk) {
        double av[4], bv[4];
        #pragma unroll
        for (int q = 0; q < 4; ++q) { av[q] = As[kk][(ty<<2)+q]; bv[q] = Bs[kk][(tx<<2)+q]; }
        #pragma unroll
        for (int ii = 0; ii < 4; ++ii)
          #pragma unroll
          for (int jj = 0; jj < 4; ++jj)
            acc[ii][jj] = fma(av[ii], bv[jj], acc[ii][jj]);
      }
    }
    #pragma unroll
    for (int ii = 0; ii < 4; ++ii)
      #pragma unroll
      for (int jj = 0; jj < 4; ++jj)
        epi((ty << 2) + ii, (tx << 2) + jj, acc[ii][jj]);
  }
}

// Dual-accumulator double-buffered variant (final64): epi(mi, ni, vy, vz).
template<int NR, typename FLD, typename FST, typename FE>
__device__ __forceinline__ void run_gemm2_db(int K, int flagv, int t,
    double (*Ps)[66], double (*W1)[66], double (*W2)[66], FLD ld, FST st, FE epi)
{
  const int lane = t & 63; const int wid = t >> 6;
  const int wr = (wid >> 1) << 5; const int wc = (wid & 1) << 5;
  const int lr = lane & 15; const int lk = lane >> 4;
  double r[NR];
  ld(0, r);
  if (flagv < 4) {
    dx4 accY[2][2] = {};
    dx4 accZ[2][2] = {};
    for (int k0 = 0; k0 < K; k0 += 16) {
      __syncthreads();
      st(k0, r);
      __syncthreads();
      if (k0 + 16 < K) ld(k0 + 16, r);
      #pragma unroll
      for (int kq = 0; kq < 4; ++kq) {
        const int kr = (kq << 2) + lk;
        const double a0 = Ps[kr][wr + lr];
        const double a1 = Ps[kr][wr + 16 + lr];
        const double y0 = W1[kr][wc + lr];
        const double y1 = W1[kr][wc + 16 + lr];
        const double z0 = W2[kr][wc + lr];
        const double z1 = W2[kr][wc + 16 + lr];
        accY[0][0] = mfma64(a0, y0, accY[0][0]);
        accY[0][1] = mfma64(a0, y1, accY[0][1]);
        accY[1][0] = mfma64(a1, y0, accY[1][0]);
        accY[1][1] = mfma64(a1, y1, accY[1][1]);
        accZ[0][0] = mfma64(a0, z0, accZ[0][0]);
        accZ[0][1] = mfma64(a0, z1, accZ[0][1]);
        accZ[1][0] = mfma64(a1, z0, accZ[1][0]);
        accZ[1][1] = mfma64(a1, z1, accZ[1][1]);
      }
    }
    #pragma unroll
    for (int tm = 0; tm < 2; ++tm)
    #pragma unroll
    for (int tn = 0; tn < 2; ++tn)
    #pragma unroll
    for (int i = 0; i < 4; ++i) {
      int mo, no;
      if (flagv == 0)      { mo = (lk << 2) + i; no = lr; }
      else if (flagv == 1) { mo = lk + (i << 2); no = lr; }
      else if (flagv == 2) { mo = lr; no = (lk << 2) + i; }
      else                 { mo = lr; no = lk + (i << 2); }
      epi(wr + tm*16 + mo, wc + tn*16 + no, accY[tm][tn][i], accZ[tm][tn][i]);
    }
  } else {
    const int tx = t & 15, ty = t >> 4;
    double aY[4][4] = {};
    double aZ[4][4] = {};
    for (int k0 = 0; k0 < K; k0 += 16) {
      __syncthreads();
      st(k0, r);
      __syncthreads();
      if (k0 + 16 < K) ld(k0 + 16, r);
      #pragma unroll
      for (int kk = 0; kk < 16; ++kk) {
        double av[4], y[4], z[4];
        #pragma unroll
        for (int q = 0; q < 4; ++q) {
          av[q] = Ps[kk][(ty<<2)+q]; y[q] = W1[kk][(tx<<2)+q]; z[q] = W2[kk][(tx<<2)+q];
        }
        #pragma unroll
        for (int ii = 0; ii < 4; ++ii)
          #pragma unroll
          for (int jj = 0; jj < 4; ++jj) {
            aY[ii][jj] = fma(av[ii], y[jj], aY[ii][jj]);
            aZ[ii][jj] = fma(av[ii], z[jj], aZ[ii][jj]);
          }
      }
    }
    #pragma unroll
    for (int ii = 0; ii < 4; ++ii)
      #pragma unroll
      for (int jj = 0; jj < 4; ++jj)
        epi((ty << 2) + ii, (tx << 2) + jj, aY[ii][jj], aZ[ii][jj]);
  }
}

// ---------------------------------------------------------------------------
// f64 tiled GEMM, mixed input types, f64 output.
// EPI: 0 none; 1 tanh(v + bias[n]); 2 (m==n ? 0 : exp(v))
// ---------------------------------------------------------------------------
template<typename TA, typename TB, int TRANSB, int EPI>
__global__ __launch_bounds__(256) void gemm64(
    const TA* __restrict__ A, const TB* __restrict__ Bm,
    const float* __restrict__ bias, double* __restrict__ C,
    int M, int Nn, int K, size_t sA, size_t sB, size_t sC,
    const int* __restrict__ flagp)
{
  A  += (size_t)blockIdx.z * sA;
  Bm += (size_t)blockIdx.z * sB;
  C  += (size_t)blockIdx.z * sC;
  __shared__ double As[16][66];
  __shared__ double Bs[16][66];
  const int t  = threadIdx.x;
  const int m0 = blockIdx.y * 64, n0 = blockIdx.x * 64;
  const int flagv = *flagp;
  auto ld = [&](int k0, double* r) {
    const int ml = t >> 2; const int kc = (t & 3) << 2;
    load4d(A + (size_t)(m0 + ml) * K + k0 + kc, r);
    if (TRANSB) {
      const int nl = t >> 2;
      load4d(Bm + (size_t)(n0 + nl) * K + k0 + kc, r + 4);
    } else {
      const int kl = t >> 4; const int nc = (t & 15) << 2;
      load4d(Bm + (size_t)(k0 + kl) * Nn + n0 + nc, r + 4);
    }
  };
  auto st = [&](int k0, double* r) {
    const int ml = t >> 2; const int kc = (t & 3) << 2;
    #pragma unroll
    for (int q = 0; q < 4; ++q) As[kc+q][ml] = r[q];
    if (TRANSB) {
      const int nl = t >> 2;
      #pragma unroll
      for (int q = 0; q < 4; ++q) Bs[kc+q][nl] = r[4+q];
    } else {
      const int kl = t >> 4; const int nc = (t & 15) << 2;
      #pragma unroll
      for (int q = 0; q < 4; ++q) Bs[kl][nc+q] = r[4+q];
    }
  };
  auto epi = [&](int mi, int ni, double v) {
    const int m = m0 + mi; const int n = n0 + ni;
    if constexpr (EPI == 1) v = tanh(v + (double)bias[n]);
    if constexpr (EPI == 2) v = (m == n) ? 0.0 : exp(v);
    C[(size_t)m * Nn + n] = v;
  };
  run_gemm_db<8>(K, flagv, t, As, Bs, ld, st, epi);
}

// ---------------------------------------------------------------------------
__global__ __launch_bounds__(256) void rexp_kernel(
    const float* __restrict__ x, const float* __restrict__ WR,
    const float* __restrict__ bR, double* __restrict__ rex)
{
  const int b = blockIdx.x, t = threadIdx.x;
  const float* xb = x + (size_t)b * N_ * D_;
  double s = 0.0;
  for (int d = t; d < D_; d += 256) s += (double)xb[d] * (double)WR[d];
  __shared__ double sm[256];
  sm[t] = s; __syncthreads();
  for (int o = 128; o > 0; o >>= 1) { if (t < o) sm[t] += sm[t + o]; __syncthreads(); }
  if (t == 0) rex[b] = exp(sm[0] + (double)bR[0]);
}

// ---------------------------------------------------------------------------
__global__ __launch_bounds__(256) void colsum64(
    const double* __restrict__ P, double* __restrict__ cs)
{
  const int bl = blockIdx.y;
  const int j = blockIdx.x * 256 + threadIdx.x;
  const double* Pb = P + (size_t)bl * N_ * N_;
  double s0 = 0.0, s1 = 0.0, s2 = 0.0, s3 = 0.0;
  for (int i = 0; i < N_; i += 4) {
    s0 += Pb[(size_t)(i+0) * N_ + j];
    s1 += Pb[(size_t)(i+1) * N_ + j];
    s2 += Pb[(size_t)(i+2) * N_ + j];
    s3 += Pb[(size_t)(i+3) * N_ + j];
  }
  cs[bl * N_ + j] = (s0 + s1) + (s2 + s3);
}

// ---------------------------------------------------------------------------
// PT = P^T (per batch), 32x32 LDS tiles. PT[k][i] = P[i][k].
// ---------------------------------------------------------------------------
__global__ __launch_bounds__(256) void transpose64(
    const double* __restrict__ P, double* __restrict__ PT)
{
  __shared__ double tile[32][33];
  const int bl = blockIdx.z;
  const double* Pb = P + (size_t)bl * N_ * N_;
  double* Tb = PT + (size_t)bl * N_ * N_;
  const int x0 = blockIdx.x * 32, y0 = blockIdx.y * 32;
  const int tx = threadIdx.x & 31, ty = threadIdx.x >> 5;   // 32 x 8
  #pragma unroll
  for (int r = 0; r < 32; r += 8)
    tile[ty + r][tx] = Pb[(size_t)(y0 + ty + r) * N_ + x0 + tx];
  __syncthreads();
  #pragma unroll
  for (int r = 0; r < 32; r += 8)
    Tb[(size_t)(x0 + ty + r) * N_ + y0 + tx] = tile[tx][ty + r];
}

// ---------------------------------------------------------------------------
// Power iteration on L^T L (virtual L) -> theta2[bl] = RTOL2 * sigma_max^2
// ---------------------------------------------------------------------------
__global__ __launch_bounds__(512) void powiter(
    const double* __restrict__ P, const double* __restrict__ PT,
    const double* __restrict__ cs, const double* __restrict__ rex,
    double* __restrict__ theta2, int b0)
{
  const int bl = blockIdx.x, t = threadIdx.x;
  const double* Pb  = P  + (size_t)bl * N_ * N_;
  const double* PTb = PT + (size_t)bl * N_ * N_;
  const double* csb = cs + (size_t)bl * N_;
  const double rx = rex[b0 + bl];
  __shared__ double v[N_], y[N_], red[512];
  v[t] = 1.0; __syncthreads();
  double sig2 = 0.0;
  for (int it = 0; it < POW_ITERS; ++it) {
    red[t] = v[t]; __syncthreads();
    for (int o = 256; o > 0; o >>= 1) { if (t < o) red[t] += red[t+o]; __syncthreads(); }
    const double sumv = red[0];
    double s;
    if (t == 0) s = rx * sumv;
    else {
      s = csb[t] * v[t];
      double d0 = 0.0, d1 = 0.0, d2 = 0.0, d3 = 0.0;
      for (int k = 0; k < N_; k += 4) {
        d0 += PTb[(size_t)(k+0) * N_ + t] * v[k+0];
        d1 += PTb[(size_t)(k+1) * N_ + t] * v[k+1];
        d2 += PTb[(size_t)(k+2) * N_ + t] * v[k+2];
        d3 += PTb[(size_t)(k+3) * N_ + t] * v[k+3];
      }
      s -= (d0 + d1) + (d2 + d3);
    }
    __syncthreads();
    y[t] = s; __syncthreads();
    const double y0 = y[0];
    double z = rx * y0 + ((t > 0) ? csb[t] * y[t] : 0.0) + Pb[t] * y0;
    {
      double d0 = 0.0, d1 = 0.0, d2 = 0.0, d3 = 0.0;
      for (int i = 0; i < N_; i += 4) {
        d0 += Pb[(size_t)(i+0) * N_ + t] * y[i+0];
        d1 += Pb[(size_t)(i+1) * N_ + t] * y[i+1];
        d2 += Pb[(size_t)(i+2) * N_ + t] * y[i+2];
        d3 += Pb[(size_t)(i+3) * N_ + t] * y[i+3];
      }
      z -= (d0 + d1) + (d2 + d3);
    }
    red[t] = z * z; __syncthreads();
    for (int o = 256; o > 0; o >>= 1) { if (t < o) red[t] += red[t+o]; __syncthreads(); }
    const double nz = sqrt(red[0]);
    sig2 = nz;
    v[t] = z / nz; __syncthreads();
  }
  if (t == 0) theta2[bl] = RTOL2 * sig2;
}

// ---------------------------------------------------------------------------
// S = L L^T + theta2 * I   (virtual L)
// ---------------------------------------------------------------------------
__global__ __launch_bounds__(256) void syrk64(
    const double* __restrict__ P, const double* __restrict__ cs,
    const double* __restrict__ rex, const double* __restrict__ th2,
    double* __restrict__ S, int b0, const int* __restrict__ flagp)
{
  const int bl = blockIdx.z;
  const double* Pb  = P + (size_t)bl * N_ * N_;
  const double* csb = cs + (size_t)bl * N_;
  const double rx = rex[b0 + bl];
  double* Sb = S + (size_t)bl * N_ * N_;
  __shared__ double As[16][66];
  __shared__ double Bs[16][66];
  const int t  = threadIdx.x;
  const int i0 = blockIdx.y * 64, j0 = blockIdx.x * 64;
  const int flagv = *flagp;
  const double l2 = th2[bl];
  auto ld = [&](int k0, double* r) {
    const int ml = t >> 2; const int kc = (t & 3) << 2;
    load4d(Pb + (size_t)(i0 + ml) * N_ + k0 + kc, r);
    load4d(Pb + (size_t)(j0 + ml) * N_ + k0 + kc, r + 4);
  };
  auto st = [&](int k0, double* r) {
    const int ml = t >> 2; const int kc = (t & 3) << 2;
    const int i = i0 + ml;
    #pragma unroll
    for (int q = 0; q < 4; ++q) {
      const int k = k0 + kc + q;
      As[kc+q][ml] = (i == 0) ? rx : ((i == k) ? csb[k] : -r[q]);
    }
    const int j = j0 + ml;
    #pragma unroll
    for (int q = 0; q < 4; ++q) {
      const int k = k0 + kc + q;
      Bs[kc+q][ml] = (j == 0) ? rx : ((j == k) ? csb[k] : -r[4+q]);
    }
  };
  auto epi = [&](int mi, int ni, double v) {
    const int ig = i0 + mi; const int jg = j0 + ni;
    if (ig == jg) v += l2;
    Sb[(size_t)ig * N_ + jg] = v;
  };
  run_gemm_db<8>(N_, flagv, t, As, Bs, ld, st, epi);
}

// ---------------------------------------------------------------------------
// Newton init: X0 = I / (1.1 * lambda_max),  lambda_max = th2*(1+RTOL2)/RTOL2.
// ---------------------------------------------------------------------------
__global__ __launch_bounds__(256) void newton_init(
    const double* __restrict__ th2, double* __restrict__ X)
{
  const size_t idx = (size_t)blockIdx.x * 256 + threadIdx.x;
  const int bl  = (int)(idx >> 18);
  const int rem = (int)(idx & ((size_t)N_ * N_ - 1));
  const double c = RTOL2 / (1.1 * th2[bl] * (1.0 + RTOL2));
  X[idx] = ((rem >> 9) == (rem & (N_ - 1))) ? c : 0.0;
}

// ---------------------------------------------------------------------------
// Ctik[i,j] = sum_k L[k,i] * Sinv[k,j]   (Ctik = L^T Sinv, virtual L)
// ---------------------------------------------------------------------------
__global__ __launch_bounds__(256) void linv64(
    const double* __restrict__ P, const double* __restrict__ cs,
    const double* __restrict__ rex, const double* __restrict__ Sinv,
    double* __restrict__ Out, int b0, const int* __restrict__ flagp)
{
  const int bl = blockIdx.z;
  const double* Pb  = P + (size_t)bl * N_ * N_;
  const double* csb = cs + (size_t)bl * N_;
  const double rx = rex[b0 + bl];
  const double* Sb = Sinv + (size_t)bl * N_ * N_;
  double* Ob = Out + (size_t)bl * N_ * N_;
  __shared__ double As[16][66];   // [k][i] = L[k0+k][i0+i]
  __shared__ double Bs[16][66];   // [k][j] = Sinv[k0+k][j0+j]
  const int t  = threadIdx.x;
  const int i0 = blockIdx.y * 64, j0 = blockIdx.x * 64;
  const int flagv = *flagp;
  auto ld = [&](int k0, double* r) {
    const int kl = t >> 4; const int c4 = (t & 15) << 2;
    const int k = k0 + kl;
    load4d(Pb + (size_t)k * N_ + i0 + c4, r);
    load4d(Sb + (size_t)k * N_ + j0 + c4, r + 4);
  };
  auto st = [&](int k0, double* r) {
    const int kl = t >> 4; const int c4 = (t & 15) << 2;
    const int k = k0 + kl;
    #pragma unroll
    for (int q = 0; q < 4; ++q) {
      const int i = i0 + c4 + q;
      As[kl][c4+q] = (k == 0) ? rx : ((k == i) ? csb[k] : -r[q]);
    }
    #pragma unroll
    for (int q = 0; q < 4; ++q) Bs[kl][c4+q] = r[4+q];
  };
  auto epi = [&](int mi, int ni, double v) {
    Ob[(size_t)(i0 + mi) * N_ + j0 + ni] = v;
  };
  run_gemm_db<8>(N_, flagv, t, As, Bs, ld, st, epi);
}

// ---------------------------------------------------------------------------
// Ghat = A * L_virtual.  Fused epilogue also emits D = I - G and R0 = 2I - G.
// ---------------------------------------------------------------------------
__global__ __launch_bounds__(256) void ghat64(
    const double* __restrict__ A, const double* __restrict__ P,
    const double* __restrict__ cs, const double* __restrict__ rex,
    double* __restrict__ OutG, double* __restrict__ OutD,
    double* __restrict__ OutR, int b0, const int* __restrict__ flagp)
{
  const int bl = blockIdx.z;
  const double* Ab  = A + (size_t)bl * N_ * N_;
  const double* Pb  = P + (size_t)bl * N_ * N_;
  const double* csb = cs + (size_t)bl * N_;
  const double rx = rex[b0 + bl];
  double* Gb = OutG + (size_t)bl * N_ * N_;
  double* Db = OutD + (size_t)bl * N_ * N_;
  double* Rb = OutR + (size_t)bl * N_ * N_;
  __shared__ double As[16][66];
  __shared__ double Bs[16][66];
  const int t  = threadIdx.x;
  const int m0 = blockIdx.y * 64, n0 = blockIdx.x * 64;
  const int flagv = *flagp;
  auto ld = [&](int k0, double* r) {
    const int ml = t >> 2; const int kc = (t & 3) << 2;
    load4d(Ab + (size_t)(m0 + ml) * N_ + k0 + kc, r);
    const int kl = t >> 4; const int nc = (t & 15) << 2;
    load4d(Pb + (size_t)(k0 + kl) * N_ + n0 + nc, r + 4);
  };
  auto st = [&](int k0, double* r) {
    const int ml = t >> 2; const int kc = (t & 3) << 2;
    #pragma unroll
    for (int q = 0; q < 4; ++q) As[kc+q][ml] = r[q];
    const int kl = t >> 4; const int nc = (t & 15) << 2;
    const int k = k0 + kl;
    #pragma unroll
    for (int q = 0; q < 4; ++q) {
      const int n = n0 + nc + q;
      Bs[kl][nc+q] = (k == 0) ? rx : ((k == n) ? csb[k] : -r[4+q]);
    }
  };
  auto epi = [&](int mi, int ni, double v) {
    const int m = m0 + mi; const int n = n0 + ni;
    const double di = (m == n) ? 1.0 : 0.0;
    const size_t off = (size_t)m * N_ + n;
    Gb[off] = v;
    Db[off] = di - v;         // D = I - G
    Rb[off] = 2.0 * di - v;   // R0 = 2I - G
  };
  run_gemm_db<8>(N_, flagv, t, As, Bs, ld, st, epi);
}

// ---------------------------------------------------------------------------
// f64 NN GEMM (batched stride N*N), full grid.
// EPI 0: C = A*B.               EPI 2: C = 3*A - 2*A*B  (smoothstep).
// EPI 4: C = 2g*A - g^2*A*B     (scaled Newton, g runtime).
// EPI 5: C = A + A*B            (Horner product accumulate).
// ---------------------------------------------------------------------------
template<int EPI>
__global__ __launch_bounds__(256) void gemm_dd(
    const double* __restrict__ A, const double* __restrict__ Bm,
    double* __restrict__ C, const int* __restrict__ flagp, double g)
{
  const size_t s = (size_t)N_ * N_;
  const double* Ab = A  + (size_t)blockIdx.z * s;
  const double* Bb = Bm + (size_t)blockIdx.z * s;
  double*       Cb = C  + (size_t)blockIdx.z * s;
  __shared__ double As[16][66];
  __shared__ double Bs[16][66];
  const int t  = threadIdx.x;
  const int m0 = blockIdx.y * 64, n0 = blockIdx.x * 64;
  const int flagv = *flagp;
  auto ld = [&](int k0, double* r) {
    const int ml = t >> 2; const int kc = (t & 3) << 2;
    load4d(Ab + (size_t)(m0 + ml) * N_ + k0 + kc, r);
    const int kl = t >> 4; const int nc = (t & 15) << 2;
    load4d(Bb + (size_t)(k0 + kl) * N_ + n0 + nc, r + 4);
  };
  auto st = [&](int k0, double* r) {
    const int ml = t >> 2; const int kc = (t & 3) << 2;
    #pragma unroll
    for (int q = 0; q < 4; ++q) As[kc+q][ml] = r[q];
    const int kl = t >> 4; const int nc = (t & 15) << 2;
    #pragma unroll
    for (int q = 0; q < 4; ++q) Bs[kl][nc+q] = r[4+q];
  };
  auto epi = [&](int mi, int ni, double v) {
    const int m = m0 + mi; const int n = n0 + ni;
    if constexpr (EPI == 2) v = 3.0 * Ab[(size_t)m * N_ + n] - 2.0 * v;
    if constexpr (EPI == 4) v = 2.0 * g * Ab[(size_t)m * N_ + n] - g * g * v;
    if constexpr (EPI == 5) v = Ab[(size_t)m * N_ + n] + v;
    Cb[(size_t)m * N_ + n] = v;
  };
  run_gemm_db<8>(N_, flagv, t, As, Bs, ld, st, epi);
}

// ---------------------------------------------------------------------------
// out[bl,i,j] = (j>0)*(P @ C)[i,j] - (i>0)*(P @ C^T)[i,j]
// ---------------------------------------------------------------------------
__global__ __launch_bounds__(256) void final64(
    const double* __restrict__ P, const double* __restrict__ X,
    float* __restrict__ Out, const int* __restrict__ flagp)
{
  const int bl = blockIdx.z;
  const double* Pb = P + (size_t)bl * N_ * N_;
  const double* Ib = X + (size_t)bl * N_ * N_;
  float*        Ob = Out + (size_t)bl * N_ * N_;
  __shared__ double Ps[16][66];
  __shared__ double W1[16][66];
  __shared__ double W2[16][66];
  const int t  = threadIdx.x;
  const int m0 = blockIdx.y * 64, n0 = blockIdx.x * 64;
  const int flagv = *flagp;
  auto ld = [&](int k0, double* r) {
    const int ml = t >> 2; const int kc = (t & 3) << 2;
    load4d(Pb + (size_t)(m0 + ml) * N_ + k0 + kc, r);
    load4d(Ib + (size_t)(n0 + ml) * N_ + k0 + kc, r + 4);
    const int kl = t >> 4; const int nc = (t & 15) << 2;
    load4d(Ib + (size_t)(k0 + kl) * N_ + n0 + nc, r + 8);
  };
  auto st = [&](int k0, double* r) {
    const int ml = t >> 2; const int kc = (t & 3) << 2;
    #pragma unroll
    for (int q = 0; q < 4; ++q) Ps[kc+q][ml] = r[q];
    #pragma unroll
    for (int q = 0; q < 4; ++q) W2[kc+q][ml] = r[4+q];
    const int kl = t >> 4; const int nc = (t & 15) << 2;
    #pragma unroll
    for (int q = 0; q < 4; ++q) W1[kl][nc+q] = r[8+q];
  };
  auto epi = [&](int mi, int ni, double vy, double vz) {
    const int m = m0 + mi; const int n = n0 + ni;
    double v = 0.0;
    if (n > 0) v += vy;
    if (m > 0) v -= vz;
    Ob[(size_t)m * N_ + n] = (float)v;
  };
  run_gemm2_db<12>(N_, flagv, t, Ps, W1, W2, ld, st, epi);
}

// ---------------------------------------------------------------------------
extern "C" void kernel_launch(void* const* d_in, const int* in_sizes, int n_in,
                              void* d_out, int out_size, void* d_ws, size_t ws_size,
                              hipStream_t stream)
{
  const float* x    = (const float*)d_in[0];
  const float* W_P  = (const float*)d_in[1];
  const float* b_P  = (const float*)d_in[2];
  const float* W_C  = (const float*)d_in[3];
  const float* b_C  = (const float*)d_in[4];
  const float* W_bl = (const float*)d_in[5];
  const float* W_R  = (const float*)d_in[6];
  const float* b_R  = (const float*)d_in[7];
  float* out = (float*)d_out;
  char*  ws8 = (char*)d_ws;

  // Workspace (bytes), peak ~144.1 MB:
  double* encS = (double*)(ws8 + 0);           // 32 MB encP/encC -> Gd, Dd
  double* Tst  = (double*)(ws8 + 33554432);    // 32 MB T8 -> PT -> Ra, Rb
  double* P8   = (double*)(ws8 + 67108864);    // 16 MB
  double* Md   = (double*)(ws8 + 83886080);    // 16 MB S (const through Newton)
  double* Vd   = (double*)(ws8 + 100663296);   // 16 MB X ping
  double* Ctik = (double*)(ws8 + 117440512);   // 16 MB T temp -> Ctik
  double* C1d  = (double*)(ws8 + 134217728);   // 16 MB X pong (ends=Sinv) -> C1
  double* csg  = (double*)(ws8 + 150994944);   // 32 KB
  double* th2  = (double*)(ws8 + 151027712);   // 64 B
  double* rex  = (double*)(ws8 + 151027776);   // 256 B
  int*    flagp= (int*)   (ws8 + 151028032);   // 4 B : MFMA layout flag
  double* Gd   = (double*)(ws8 + 0);
  double* Dd   = (double*)(ws8 + 16777216);
  double* Ra   = (double*)(ws8 + 33554432);
  double* Rb   = (double*)(ws8 + 50331648);
  double* PTd  = (double*)(ws8 + 33554432);    // PT aliases Tst/Ra (dead then)

  // Host-computed scaled-Newton gamma schedule (data-independent).
  double gam[J_NEWT];
  {
    double a = RTOL2 / (1.1 * (1.0 + RTOL2));
    double b = (1.0 / 1.1) * 1.08;
    for (int k = 0; k < J_NEWT; ++k) {
      double g = 2.0 / (a + b);
      if (g < 1.0) g = 1.0;
      gam[k] = g;
      double ga = g * a;
      a = ga * (2.0 - ga);
      if (a > 1.0) a = 1.0;
      b = 1.0;
    }
  }

  const dim3 blk(256);
  const size_t sNH = (size_t)N_ * H_;
  const size_t sNN = (size_t)N_ * N_;
  const dim3 g64(N_/64, N_/64, NB);
  const dim3 gEw((NB * N_ * N_) / 256);

  // On-device MFMA D-layout probe (4 conventions + VALU fallback).
  mfma_probe<<<dim3(1), dim3(64), 0, stream>>>(flagp);
  rexp_kernel<<<dim3(B_), blk, 0, stream>>>(x, W_R, b_R, rex);

  for (int g = 0; g < 4; ++g) {
    const int b0 = g * NB;
    const float* xg = x + (size_t)b0 * N_ * D_;
    // ---- upstream (f64) ----
    gemm64<float,float,1,1><<<dim3(H_/64, M8/64, 1), blk, 0, stream>>>(
        xg, W_P, b_P, encS, M8, H_, D_, 0, 0, 0, flagp);
    gemm64<double,float,0,0><<<dim3(H_/64, M8/64, 1), blk, 0, stream>>>(
        encS, W_bl, nullptr, Tst, M8, H_, H_, 0, 0, 0, flagp);
    gemm64<float,float,1,1><<<dim3(H_/64, M8/64, 1), blk, 0, stream>>>(
        xg, W_C, b_C, encS, M8, H_, D_, 0, 0, 0, flagp);
    gemm64<double,double,1,2><<<g64, blk, 0, stream>>>(
        Tst, encS, nullptr, P8, N_, N_, H_, sNH, sNH, sNN, flagp);
    colsum64<<<dim3(N_/256, NB), blk, 0, stream>>>(P8, csg);
    // ---- PT = P^T (Tst dead now), then theta^2 via coalesced power iter ----
    transpose64<<<dim3(N_/32, N_/32, NB), blk, 0, stream>>>(P8, PTd);
    powiter<<<dim3(NB), dim3(512), 0, stream>>>(P8, PTd, csg, rex, th2, b0);
    // ---- S = L L^T + theta^2 I ----
    syrk64<<<g64, blk, 0, stream>>>(P8, csg, rex, th2, Md, b0, flagp);
    // ---- Sinv via scaled Newton: X' = 2g X - g^2 X (S X) ----
    newton_init<<<gEw, blk, 0, stream>>>(th2, Vd);
    for (int it = 0; it < J_NEWT; ++it) {
      const double* Xin  = (it & 1) ? C1d : Vd;
      double*       Xout = (it & 1) ? Vd : C1d;
      gemm_dd<0><<<g64, blk, 0, stream>>>(Md, Xin, Ctik, flagp, 0.0);       // T = S X
      gemm_dd<4><<<g64, blk, 0, stream>>>(Xin, Ctik, Xout, flagp, gam[it]); // X'
    }
    // J_NEWT=15: last it=14 (even) -> Sinv lands in C1d.
    // ---- C_tik = L^T Sinv ----
    linv64<<<g64, blk, 0, stream>>>(P8, csg, rex, C1d, Ctik, b0, flagp);
    // ---- Ghat = C_tik * L ; fused D = I - G and R0 = 2I - G ----
    ghat64<<<g64, blk, 0, stream>>>(Ctik, P8, csg, rex, Gd, Dd, Ra, b0, flagp);
    // ---- R = (I+D)(I+D^2)(I+D^4)(I+D^8)(I+D^16)  (deg-31) ----
    gemm_dd<0><<<g64, blk, 0, stream>>>(Dd, Dd, Rb, flagp, 0.0);   // D2
    gemm_dd<5><<<g64, blk, 0, stream>>>(Ra, Rb, C1d, flagp, 0.0);  // R *= (I+D2)
    gemm_dd<0><<<g64, blk, 0, stream>>>(Rb, Rb, Dd, flagp, 0.0);   // D4
    gemm_dd<5><<<g64, blk, 0, stream>>>(C1d, Dd, Ra, flagp, 0.0);  // R *= (I+D4)
    gemm_dd<0><<<g64, blk, 0, stream>>>(Dd, Dd, Rb, flagp, 0.0);   // D8
    gemm_dd<5><<<g64, blk, 0, stream>>>(Ra, Rb, C1d, flagp, 0.0);  // R *= (I+D8)
    gemm_dd<0><<<g64, blk, 0, stream>>>(Rb, Rb, Dd, flagp, 0.0);   // D16
    gemm_dd<5><<<g64, blk, 0, stream>>>(C1d, Dd, Ra, flagp, 0.0);  // R *= (I+D16)
    // ---- C1 = R * C_tik ----
    gemm_dd<0><<<g64, blk, 0, stream>>>(Ra, Ctik, C1d, flagp, 0.0);
    // ---- smoothstep^J on F = Ghat (ping Gd <-> Dd, T in Ra) ----
    double* F = Gd; double* Falt = Dd;
    for (int jit = 0; jit < J_SS; ++jit) {
      gemm_dd<0><<<g64, blk, 0, stream>>>(F, F, Ra, flagp, 0.0);    // T = F*F
      gemm_dd<2><<<g64, blk, 0, stream>>>(Ra, F, Falt, flagp, 0.0); // F' = 3T - 2TF
      double* tmp = F; F = Falt; Falt = tmp;
    }
    // ---- C_sharp = F * C1 ----
    gemm_dd<0><<<g64, blk, 0, stream>>>(F, C1d, Ctik, flagp, 0.0);
    // ---- A ----
    final64<<<g64, blk, 0, stream>>>(P8, Ctik, out + (size_t)b0 * sNN, flagp);
  }
}